// Round 8
// baseline (437.055 us; speedup 1.0000x reference)
//
#include <hip/hip_runtime.h>

// Problem constants
static constexpr int kBS    = 8;
static constexpr int kNROI  = 128;
static constexpr int kR     = kBS * kNROI;   // 1024 rows
static constexpr int kCH    = 1280;
static constexpr int kH     = 64;
static constexpr int kW     = 64;
static constexpr int kPIX   = kH * kW;       // 4096
static constexpr int kINNER = 5120;
static constexpr int kOUTC  = 1024;
static constexpr int kXE    = 2 * kOUTC;     // 2048 concat width
static constexpr int kE2    = 256;           // size-MLP hidden 2
static constexpr int kLB    = 144;           // max consolidated list length

typedef _Float16 half8 __attribute__((ext_vector_type(8)));   // f16x8 MFMA A/B frag
typedef float floatx4 __attribute__((ext_vector_type(4)));    // MFMA C/D frag

// Async global->LDS 16B copy. LDS dest must be wave-uniform base + lane*16,
// which our chunk-index==threadIdx staging layout satisfies exactly.
__device__ __forceinline__ void gload_lds16(const _Float16* g, _Float16* l) {
    __builtin_amdgcn_global_load_lds(
        (const __attribute__((address_space(1))) void*)g,
        (__attribute__((address_space(3))) void*)l,
        16, 0, 0);
}

// ---------------------------------------------------------------------------
// Consolidated ROI weights: distinct pixel rows/cols with summed separable
// weights (verified rounds 6/7). invCount folded into weights downstream.
// ---------------------------------------------------------------------------
struct RoiW {
    int   ymin, xmin, nyd, nxd;
    float ywt[12], xwt[12];
    float invCount;
};

__device__ inline void build_wcons(const float* __restrict__ bboxes, int r, RoiW* L) {
    const float x1 = bboxes[r * 4 + 0] * 0.125f - 0.5f;
    const float y1 = bboxes[r * 4 + 1] * 0.125f - 0.5f;
    const float x2 = bboxes[r * 4 + 2] * 0.125f - 0.5f;
    const float y2 = bboxes[r * 4 + 3] * 0.125f - 0.5f;
    const float rw = x2 - x1, rh = y2 - y1;
    const float gwf = fminf(fmaxf(ceilf(rw), 1.0f), 8.0f);
    const float ghf = fminf(fmaxf(ceilf(rh), 1.0f), 8.0f);
    const int gw = (int)gwf, gh = (int)ghf;
    L->invCount = 1.0f / (gwf * ghf);

#pragma unroll
    for (int i = 0; i < 12; ++i) { L->ywt[i] = 0.0f; L->xwt[i] = 0.0f; }

    int ymin = 0, last = 0;
    for (int g = 0; g < gh; ++g) {
        const float c   = y1 + ((float)g + 0.5f) * rh / ghf;
        const bool oob  = (c < -1.0f) || (c > 64.0f);
        const float cc  = fmaxf(c, 0.0f);
        const float lo0 = floorf(cc);
        const bool hic  = (lo0 >= 63.0f);
        const int lo    = (int)fminf(lo0, 63.0f);
        const int hi    = (int)fminf(lo0 + 1.0f, 63.0f);
        const float fr  = hic ? 0.0f : (cc - lo0);
        const float m   = oob ? 0.0f : 1.0f;
        if (g == 0) ymin = lo;
        const int il = min(lo - ymin, 11);
        const int ih = min(hi - ymin, 11);
        L->ywt[il] += m * (1.0f - fr);
        L->ywt[ih] += m * fr;
        last = hi;
    }
    L->ymin = ymin;
    L->nyd  = min(last - ymin + 1, 12);

    int xmin = 0; last = 0;
    for (int g = 0; g < gw; ++g) {
        const float c   = x1 + ((float)g + 0.5f) * rw / gwf;
        const bool oob  = (c < -1.0f) || (c > 64.0f);
        const float cc  = fmaxf(c, 0.0f);
        const float lo0 = floorf(cc);
        const bool hic  = (lo0 >= 63.0f);
        const int lo    = (int)fminf(lo0, 63.0f);
        const int hi    = (int)fminf(lo0 + 1.0f, 63.0f);
        const float fr  = hic ? 0.0f : (cc - lo0);
        const float m   = oob ? 0.0f : 1.0f;
        if (g == 0) xmin = lo;
        const int il = min(lo - xmin, 11);
        const int ih = min(hi - xmin, 11);
        L->xwt[il] += m * (1.0f - fr);
        L->xwt[ih] += m * fr;
        last = hi;
    }
    L->xmin = xmin;
    L->nxd  = min(last - xmin + 1, 12);
}

// ---------------------------------------------------------------------------
// PREP mega-kernel: weight converts + size-MLP 1+2 + per-ROI gather lists.
// Flat 256 threads. Block ranges:
//   [0, 13824)      : weight transpose+convert 32x32 tiles (W1, W2, O, S3)
//   [13824, 14080)  : size-MLP layers 1+2 (4 ROIs per block)
//   [14080, 14084)  : ROI list build+expand, thread = one ROI (1024 total)
// (z transpose is GONE: the gather now reads fp32 z planes directly.)
// ---------------------------------------------------------------------------
static constexpr int kPrepConvEnd = 13824;
static constexpr int kPrepMlpEnd  = 14080;
static constexpr int kPrepAllEnd  = 14084;

__global__ __launch_bounds__(256) void prep_all(const float* __restrict__ W1,
                                                const float* __restrict__ W2,
                                                const float* __restrict__ O,
                                                const float* __restrict__ S3,
                                                _Float16* __restrict__ W1t,
                                                _Float16* __restrict__ W2t,
                                                _Float16* __restrict__ Ot,
                                                _Float16* __restrict__ S3t,
                                                const float* __restrict__ bboxes,
                                                const float* __restrict__ S1,
                                                const float* __restrict__ sb1,
                                                const float* __restrict__ S2,
                                                const float* __restrict__ sb2,
                                                _Float16* __restrict__ h2f,
                                                int2* __restrict__ lst,
                                                int* __restrict__ npA) {
    __shared__ float smem[32 * 33];   // 4.2 KB, reused by branches
    const int bid = blockIdx.x;
    const int t   = threadIdx.x;      // 0..255

    if (bid < kPrepConvEnd) {
        // ---- weight convert+transpose: W (K x N) fp32 -> Wt (N x K) f16 ----
        const float* W; _Float16* Wt; int K, N, tile;
        if (bid < 6400)        { W = W1; Wt = W1t; K = kCH;    N = kINNER; tile = bid; }
        else if (bid < 11520)  { W = W2; Wt = W2t; K = kINNER; N = kOUTC;  tile = bid - 6400; }
        else if (bid < 13568)  { W = O;  Wt = Ot;  K = kXE;    N = kOUTC;  tile = bid - 11520; }
        else                   { W = S3; Wt = S3t; K = kE2;    N = kOUTC;  tile = bid - 13568; }
        const int nt = N / 32;
        const int n0 = (tile % nt) * 32;
        const int k0 = (tile / nt) * 32;
        {   // load 32x32 floats as 256 float4 (row = k-local, col = n-local)
            const int row = t >> 3;          // 0..31
            const int c4  = (t & 7) * 4;     // 0..28
            const float4 v = *(const float4*)&W[(size_t)(k0 + row) * N + n0 + c4];
            float* tl = smem + row * 33 + c4;
            tl[0] = v.x; tl[1] = v.y; tl[2] = v.z; tl[3] = v.w;
        }
        __syncthreads();
        {   // transposed store: 4 k packed per thread -> uint2 (8B)
            const int n  = t >> 3;           // 0..31
            const int k4 = (t & 7) * 4;      // 0..28
            union { _Float16 h[4]; uint2 u; } pk;
#pragma unroll
            for (int j = 0; j < 4; ++j) pk.h[j] = (_Float16)smem[(k4 + j) * 33 + n];
            *(uint2*)&Wt[(size_t)(n0 + n) * K + k0 + k4] = pk.u;
        }
    } else if (bid < kPrepMlpEnd) {
        // ---- size-MLP layers 1+2: 2 -> 64 -> 256, 4 rows/block ----
        const int r0 = (bid - kPrepConvEnd) * 4;
        float* sz = smem;             // [4][2]
        float* h1 = smem + 8;         // [4][64]
        if (t < 8) {
            const int row = t >> 1;
            const int c   = t & 1;
            const float* bb = bboxes + (size_t)(r0 + row) * 4;
            sz[row * 2 + c] = (c == 0) ? (bb[3] - bb[1]) : (bb[2] - bb[0]);
        }
        __syncthreads();
        {   // layer 1: 4 rows x 64 = 256 items, one per thread
            const int row = t >> 6;
            const int j   = t & 63;
            const float v = sz[row * 2] * S1[j] + sz[row * 2 + 1] * S1[64 + j] + sb1[j];
            h1[row * 64 + j] = fmaxf(v, 0.0f);
        }
        __syncthreads();
        {   // layer 2: j = t, 4 rows register-blocked
            float acc[4];
            const float b = sb2[t];
#pragma unroll
            for (int row = 0; row < 4; ++row) acc[row] = b;
#pragma unroll 16
            for (int k = 0; k < 64; ++k) {
                const float w = S2[k * 256 + t];
#pragma unroll
                for (int row = 0; row < 4; ++row) acc[row] += h1[row * 64 + k] * w;
            }
#pragma unroll
            for (int row = 0; row < 4; ++row)
                h2f[(size_t)(r0 + row) * kE2 + t] = (_Float16)fmaxf(acc[row], 0.0f);
        }
    } else {
        // ---- ROI list build + expand: one thread per ROI ----
        const int r = (bid - kPrepMlpEnd) * 256 + t;   // 0..1023
        RoiW L;
        build_wcons(bboxes, r, &L);
        int2* lr = lst + (size_t)r * kLB;
        int p = 0;
        for (int iy = 0; iy < L.nyd; ++iy) {
            const float wy = L.ywt[iy] * L.invCount;
            const int yb   = (L.ymin + iy) * kW + L.xmin;
            for (int ix = 0; ix < L.nxd; ++ix) {
                const float w = wy * L.xwt[ix];
                if (w != 0.0f) {
                    int2 e; e.x = yb + ix; e.y = __float_as_int(w);
                    lr[p++] = e;
                }
            }
        }
        npA[r] = p;
    }
}

// ---------------------------------------------------------------------------
// ROI gather from fp32 z channel planes staged in LDS.
// Block = (channel-group of 4, image). Load 4 contiguous 16 KB planes
// (coalesced float4) into LDS (padded stride), then all 128 ROIs x 4 channels
// gather via precomputed (offset, weight) lists. Every z byte read ONCE.
// LDS 64.3 KB -> 2 blocks/CU. Grid (320, 8) = 2560 blocks.
// ---------------------------------------------------------------------------
static constexpr int kPC = 4;       // planes per block
static constexpr int kPS = 4112;    // padded plane stride in floats (16B-aligned)

__global__ __launch_bounds__(256) void roi_gather_planes(const float* __restrict__ z,
                                                         const int2* __restrict__ lst,
                                                         const int* __restrict__ npA,
                                                         _Float16* __restrict__ x) {
    __shared__ float pl[kPC * kPS];   // 64.3 KB
    const int chg = blockIdx.x;       // 0..319
    const int b   = blockIdx.y;       // 0..7
    const int c0  = chg * kPC;
    const int t   = threadIdx.x;
    const float* zb = z + ((size_t)b * kCH + c0) * kPIX;
    // load: 4 planes = 4096 float4, 16 per thread, fully coalesced
#pragma unroll
    for (int i = 0; i < 16; ++i) {
        const int idx = t + i * 256;        // float4 index 0..4095
        const int ch  = idx >> 10;          // 0..3
        const int w4  = (idx & 1023) * 4;   // float offset in plane
        const float4 v = *(const float4*)&zb[(size_t)ch * kPIX + w4];
        *(float4*)&pl[ch * kPS + w4] = v;
    }
    __syncthreads();
    const int ch   = t & 3;
    const int slot = t >> 2;               // 0..63
    const float* plc = pl + ch * kPS;
#pragma unroll
    for (int rr = 0; rr < 2; ++rr) {
        const int r = b * kNROI + slot + rr * 64;
        const int np = npA[r];
        const int2* lr = lst + (size_t)r * kLB;
        float acc = 0.0f;
        for (int p = 0; p < np; ++p) {
            const int2 e = lr[p];
            acc += __int_as_float(e.y) * plc[e.x];
        }
        x[(size_t)r * kCH + c0 + ch] = (_Float16)acc;
    }
}

// ---------------------------------------------------------------------------
// f16 MFMA GEMM (NT), 128x128 tile, BK=32, 256 threads = 4 waves.
// Double-buffered global_load_lds staging (verified rounds 3/5/6/7).
// Split-K partial (blockIdx.z), raw fp32 plane store -> P.
// ---------------------------------------------------------------------------
template <int NSPLIT>
__global__ __launch_bounds__(256) void gemm_f16_sk(const _Float16* __restrict__ A,
                                                   const _Float16* __restrict__ Bt,
                                                   float* __restrict__ P,
                                                   int Kfull) {
    __shared__ _Float16 As[2][128 * 32];
    __shared__ _Float16 Bs[2][128 * 32];
    const int t    = threadIdx.x;
    const int lane = t & 63;
    const int wave = t >> 6;
    const int m0 = blockIdx.y * 128, n0 = blockIdx.x * 128;
    const int Ksplit = Kfull / NSPLIT;
    const int s  = blockIdx.z;
    const int Nn = gridDim.x * 128;
    const int Mm = gridDim.y * 128;

    const int c0 = t, c1 = t + 256;
    const _Float16* Ag0 = A + (size_t)(m0 + (c0 >> 2)) * Kfull + (c0 & 3) * 8 + s * Ksplit;
    const _Float16* Ag1 = A + (size_t)(m0 + (c1 >> 2)) * Kfull + (c1 & 3) * 8 + s * Ksplit;
    const _Float16* Bg0 = Bt + (size_t)(n0 + (c0 >> 2)) * Kfull + (c0 & 3) * 8 + s * Ksplit;
    const _Float16* Bg1 = Bt + (size_t)(n0 + (c1 >> 2)) * Kfull + (c1 & 3) * 8 + s * Ksplit;

    const int wm = (wave >> 1) * 64;
    const int wn = (wave & 1) * 64;
    const int fm = lane & 15;
    const int kq = (lane >> 4) * 8;

    floatx4 acc[4][4];
#pragma unroll
    for (int i = 0; i < 4; ++i)
#pragma unroll
        for (int j = 0; j < 4; ++j) acc[i][j] = (floatx4){0.f, 0.f, 0.f, 0.f};

    const int nsteps = Ksplit / 32;
    gload_lds16(Ag0, &As[0][c0 * 8]);
    gload_lds16(Ag1, &As[0][c1 * 8]);
    gload_lds16(Bg0, &Bs[0][c0 * 8]);
    gload_lds16(Bg1, &Bs[0][c1 * 8]);
    __syncthreads();

    for (int ks = 0; ks < nsteps; ++ks) {
        const int cur = ks & 1;
        if (ks + 1 < nsteps) {
            const int kn = (ks + 1) * 32;
            gload_lds16(Ag0 + kn, &As[cur ^ 1][c0 * 8]);
            gload_lds16(Ag1 + kn, &As[cur ^ 1][c1 * 8]);
            gload_lds16(Bg0 + kn, &Bs[cur ^ 1][c0 * 8]);
            gload_lds16(Bg1 + kn, &Bs[cur ^ 1][c1 * 8]);
        }
        half8 af[4], bfv[4];
#pragma unroll
        for (int i = 0; i < 4; ++i)
            af[i] = *(const half8*)&As[cur][(wm + i * 16 + fm) * 32 + kq];
#pragma unroll
        for (int j = 0; j < 4; ++j)
            bfv[j] = *(const half8*)&Bs[cur][(wn + j * 16 + fm) * 32 + kq];
#pragma unroll
        for (int i = 0; i < 4; ++i)
#pragma unroll
            for (int j = 0; j < 4; ++j)
                acc[i][j] = __builtin_amdgcn_mfma_f32_16x16x32_f16(af[i], bfv[j], acc[i][j], 0, 0, 0);
        __syncthreads();
    }

    float* Pp = P + (size_t)s * Mm * Nn;
    const int qr = (lane >> 4) * 4;
#pragma unroll
    for (int j = 0; j < 4; ++j) {
        const int col = n0 + wn + j * 16 + fm;
#pragma unroll
        for (int i = 0; i < 4; ++i) {
            const int row = m0 + wm + i * 16 + qr;
#pragma unroll
            for (int rr = 0; rr < 4; ++rr)
                Pp[(size_t)(row + rr) * Nn + col] = acc[i][j][rr];
        }
    }
}

// ---------------------------------------------------------------------------
// DUAL fused GEMM: S3-embedding GEMM (64 blocks) + GEMM1 (320 blocks) in one
// launch (verified rounds 6/7).
// ---------------------------------------------------------------------------
__global__ __launch_bounds__(256) void gemm_dual(const _Float16* __restrict__ h2f,
                                                 const _Float16* __restrict__ S3t,
                                                 const float* __restrict__ sb3,
                                                 _Float16* __restrict__ xeR,
                                                 const _Float16* __restrict__ x,
                                                 const _Float16* __restrict__ W1t,
                                                 const float* __restrict__ b1,
                                                 _Float16* __restrict__ h) {
    __shared__ _Float16 As[2][128 * 32];
    __shared__ _Float16 Bs[2][128 * 32];
    const int bid = blockIdx.x;
    const _Float16* A; const _Float16* Bt; const float* bias; _Float16* Out;
    int Kfull, ldc, nbn, tile; bool relu;
    if (bid < 64) {
        A = h2f; Bt = S3t; bias = sb3; Out = xeR;
        Kfull = kE2; ldc = kXE; relu = false; nbn = kOUTC / 128; tile = bid;
    } else {
        A = x; Bt = W1t; bias = b1; Out = h;
        Kfull = kCH; ldc = kINNER; relu = true; nbn = kINNER / 128; tile = bid - 64;
    }
    const int n0 = (tile % nbn) * 128;
    const int m0 = (tile / nbn) * 128;

    const int t    = threadIdx.x;
    const int lane = t & 63;
    const int wave = t >> 6;

    const int c0 = t, c1 = t + 256;
    const _Float16* Ag0 = A + (size_t)(m0 + (c0 >> 2)) * Kfull + (c0 & 3) * 8;
    const _Float16* Ag1 = A + (size_t)(m0 + (c1 >> 2)) * Kfull + (c1 & 3) * 8;
    const _Float16* Bg0 = Bt + (size_t)(n0 + (c0 >> 2)) * Kfull + (c0 & 3) * 8;
    const _Float16* Bg1 = Bt + (size_t)(n0 + (c1 >> 2)) * Kfull + (c1 & 3) * 8;

    const int wm = (wave >> 1) * 64;
    const int wn = (wave & 1) * 64;
    const int fm = lane & 15;
    const int kq = (lane >> 4) * 8;

    floatx4 acc[4][4];
#pragma unroll
    for (int i = 0; i < 4; ++i)
#pragma unroll
        for (int j = 0; j < 4; ++j) acc[i][j] = (floatx4){0.f, 0.f, 0.f, 0.f};

    const int nsteps = Kfull / 32;
    gload_lds16(Ag0, &As[0][c0 * 8]);
    gload_lds16(Ag1, &As[0][c1 * 8]);
    gload_lds16(Bg0, &Bs[0][c0 * 8]);
    gload_lds16(Bg1, &Bs[0][c1 * 8]);
    __syncthreads();

    for (int ks = 0; ks < nsteps; ++ks) {
        const int cur = ks & 1;
        if (ks + 1 < nsteps) {
            const int kn = (ks + 1) * 32;
            gload_lds16(Ag0 + kn, &As[cur ^ 1][c0 * 8]);
            gload_lds16(Ag1 + kn, &As[cur ^ 1][c1 * 8]);
            gload_lds16(Bg0 + kn, &Bs[cur ^ 1][c0 * 8]);
            gload_lds16(Bg1 + kn, &Bs[cur ^ 1][c1 * 8]);
        }
        half8 af[4], bfv[4];
#pragma unroll
        for (int i = 0; i < 4; ++i)
            af[i] = *(const half8*)&As[cur][(wm + i * 16 + fm) * 32 + kq];
#pragma unroll
        for (int j = 0; j < 4; ++j)
            bfv[j] = *(const half8*)&Bs[cur][(wn + j * 16 + fm) * 32 + kq];
#pragma unroll
        for (int i = 0; i < 4; ++i)
#pragma unroll
            for (int j = 0; j < 4; ++j)
                acc[i][j] = __builtin_amdgcn_mfma_f32_16x16x32_f16(af[i], bfv[j], acc[i][j], 0, 0, 0);
        __syncthreads();
    }

    // Epilogue: bias (+relu) -> f16 at ldc. C/D: col = lane&15, row = (lane>>4)*4+rr
    const int qr = (lane >> 4) * 4;
#pragma unroll
    for (int j = 0; j < 4; ++j) {
        const int col = n0 + wn + j * 16 + fm;
        const float bv = bias[col];
#pragma unroll
        for (int i = 0; i < 4; ++i) {
            const int row = m0 + wm + i * 16 + qr;
#pragma unroll
            for (int rr = 0; rr < 4; ++rr) {
                float v = acc[i][j][rr] + bv;
                if (relu) v = fmaxf(v, 0.f);
                Out[(size_t)(row + rr) * ldc + col] = (_Float16)v;
            }
        }
    }
}

// ---------------------------------------------------------------------------
// Split-K reduce + bias + (relu) + convert.
// ---------------------------------------------------------------------------
template <bool RELU, bool F16OUT, int NSPLIT>
__global__ __launch_bounds__(256) void reduce_splitk(const float* __restrict__ P,
                                                     const float* __restrict__ bias,
                                                     void* __restrict__ Cout,
                                                     int Nn, int ldc) {
    const size_t idx = ((size_t)blockIdx.x * 256 + threadIdx.x) * 4;
    const size_t MN  = (size_t)gridDim.x * 1024;
    const int m = (int)(idx / (size_t)Nn);
    const int n = (int)(idx % (size_t)Nn);
    float4 acc = *(const float4*)(P + idx);
#pragma unroll
    for (int s = 1; s < NSPLIT; ++s) {
        const float4 v = *(const float4*)(P + (size_t)s * MN + idx);
        acc.x += v.x; acc.y += v.y; acc.z += v.z; acc.w += v.w;
    }
    const float4 b4 = *(const float4*)(bias + n);
    acc.x += b4.x; acc.y += b4.y; acc.z += b4.z; acc.w += b4.w;
    if (RELU) {
        acc.x = fmaxf(acc.x, 0.f); acc.y = fmaxf(acc.y, 0.f);
        acc.z = fmaxf(acc.z, 0.f); acc.w = fmaxf(acc.w, 0.f);
    }
    if (F16OUT) {
        union { _Float16 h[4]; uint2 u; } pk;
        pk.h[0] = (_Float16)acc.x; pk.h[1] = (_Float16)acc.y;
        pk.h[2] = (_Float16)acc.z; pk.h[3] = (_Float16)acc.w;
        *(uint2*)((_Float16*)Cout + (size_t)m * ldc + n) = pk.u;
    } else {
        *(float4*)((float*)Cout + (size_t)m * ldc + n) = acc;
    }
}

// ---------------------------------------------------------------------------
extern "C" void kernel_launch(void* const* d_in, const int* in_sizes, int n_in,
                              void* d_out, int out_size, void* d_ws, size_t ws_size,
                              hipStream_t stream) {
    (void)in_sizes; (void)n_in; (void)out_size; (void)ws_size;
    const float* z   = (const float*)d_in[0];
    const float* bb  = (const float*)d_in[1];
    const float* W1  = (const float*)d_in[2];
    const float* b1  = (const float*)d_in[3];
    const float* W2  = (const float*)d_in[4];
    const float* b2  = (const float*)d_in[5];
    const float* S1  = (const float*)d_in[6];
    const float* sb1 = (const float*)d_in[7];
    const float* S2  = (const float*)d_in[8];
    const float* sb2 = (const float*)d_in[9];
    const float* S3  = (const float*)d_in[10];
    const float* sb3 = (const float*)d_in[11];
    const float* O   = (const float*)d_in[12];
    const float* ob  = (const float*)d_in[13];
    float* out = (float*)d_out;

    char* ws = (char*)d_ws;
    size_t off = 0;
    auto alloc = [&](size_t bytes) {
        void* p = ws + off;
        off += (bytes + 255) & ~(size_t)255;
        return p;
    };
    _Float16* x    = (_Float16*)alloc((size_t)kR * kCH * 2);        //  2.6 MB
    _Float16* h    = (_Float16*)alloc((size_t)kR * kINNER * 2);     // 10.5 MB
    _Float16* xe   = (_Float16*)alloc((size_t)kR * kXE * 2);        //  4.2 MB
    _Float16* W1t  = (_Float16*)alloc((size_t)kINNER * kCH * 2);    // 13.1 MB
    _Float16* W2t  = (_Float16*)alloc((size_t)kOUTC * kINNER * 2);  // 10.5 MB
    _Float16* Ot   = (_Float16*)alloc((size_t)kOUTC * kXE * 2);     //  4.2 MB
    _Float16* S3t  = (_Float16*)alloc((size_t)kOUTC * kE2 * 2);     //  0.5 MB
    _Float16* h2f  = (_Float16*)alloc((size_t)kR * kE2 * 2);        //  0.5 MB
    int2*     lst  = (int2*)alloc((size_t)kR * kLB * 8);            //  1.2 MB
    int*      npA  = (int*)alloc((size_t)kR * 4);                   //  4 KB
    float*    P    = (float*)alloc((size_t)8 * kR * kOUTC * 4);     // 33.6 MB

    // 0) all prep (weight converts + size-MLP 1+2 + ROI lists) in one launch
    hipLaunchKernelGGL(prep_all, dim3(kPrepAllEnd), dim3(256), 0, stream,
                       W1, W2, O, S3, W1t, W2t, Ot, S3t,
                       bb, S1, sb1, S2, sb2, h2f, lst, npA);

    // 1) ROI-align features from fp32 z planes -> x (1024 x 1280 f16)
    hipLaunchKernelGGL(roi_gather_planes, dim3(kCH / kPC, kBS), dim3(256), 0, stream,
                       z, lst, npA, x);

    // 2) dual fused GEMM: S3-embedding (64 blocks) + GEMM1 (320 blocks)
    hipLaunchKernelGGL(gemm_dual, dim3(64 + (kINNER / 128) * (kR / 128)), dim3(256), 0,
                       stream, h2f, S3t, sb3, xe + kOUTC, x, W1t, b1, h);

    // 3) xe[:, 0:1024] = h @ W2 + b2: split-K x8 (512 blocks = 2/CU, 20 k-steps)
    hipLaunchKernelGGL((gemm_f16_sk<8>), dim3(kOUTC / 128, kR / 128, 8), dim3(256), 0,
                       stream, h, W2t, P, kINNER);
    hipLaunchKernelGGL((reduce_splitk<false, true, 8>),
                       dim3((size_t)kR * kOUTC / 1024), dim3(256), 0, stream,
                       P, b2, xe, kOUTC, kXE);

    // 4) out = xe @ O + ob: split-K x8 (512 blocks = 2/CU, 8 k-steps)
    hipLaunchKernelGGL((gemm_f16_sk<8>), dim3(kOUTC / 128, kR / 128, 8), dim3(256), 0,
                       stream, xe, Ot, P, kXE);
    hipLaunchKernelGGL((reduce_splitk<false, false, 8>),
                       dim3((size_t)kR * kOUTC / 1024), dim3(256), 0, stream,
                       P, ob, out, kOUTC, kOUTC);
}

// Round 9
// 406.883 us; speedup vs baseline: 1.0742x; 1.0742x over previous
//
#include <hip/hip_runtime.h>

// Problem constants
static constexpr int kBS    = 8;
static constexpr int kNROI  = 128;
static constexpr int kR     = kBS * kNROI;   // 1024 rows
static constexpr int kCH    = 1280;
static constexpr int kH     = 64;
static constexpr int kW     = 64;
static constexpr int kPIX   = kH * kW;       // 4096
static constexpr int kINNER = 5120;
static constexpr int kOUTC  = 1024;
static constexpr int kXE    = 2 * kOUTC;     // 2048 concat width
static constexpr int kE2    = 256;           // size-MLP hidden 2
static constexpr int kLB    = 144;           // max consolidated list length

typedef _Float16 half8 __attribute__((ext_vector_type(8)));   // f16x8 MFMA A/B frag
typedef float floatx4 __attribute__((ext_vector_type(4)));    // MFMA C/D frag

// Async global->LDS 16B copy. LDS dest must be wave-uniform base + lane*16,
// which our chunk-index==threadIdx staging layout satisfies exactly.
__device__ __forceinline__ void gload_lds16(const _Float16* g, _Float16* l) {
    __builtin_amdgcn_global_load_lds(
        (const __attribute__((address_space(1))) void*)g,
        (__attribute__((address_space(3))) void*)l,
        16, 0, 0);
}

// ---------------------------------------------------------------------------
// PREP mega-kernel: ROI gather lists + size-MLP 1+2 + weight converts.
// Flat 256 threads. Block ranges (list blocks FIRST so they overlap the
// conv blocks instead of running as a serial tail):
//   [0, 4)        : ROI list build+expand, 1 thread/ROI, LDS-backed weights
//   [4, 260)      : size-MLP layers 1+2 (4 ROIs per block)
//   [260, 14084)  : weight transpose+convert 32x32 tiles (W1, W2, O, S3)
// ---------------------------------------------------------------------------
static constexpr int kPrepListEnd = 4;
static constexpr int kPrepMlpEnd  = 260;
static constexpr int kPrepAllEnd  = 260 + 13824;   // 14084

__global__ __launch_bounds__(256) void prep_all(const float* __restrict__ W1,
                                                const float* __restrict__ W2,
                                                const float* __restrict__ O,
                                                const float* __restrict__ S3,
                                                _Float16* __restrict__ W1t,
                                                _Float16* __restrict__ W2t,
                                                _Float16* __restrict__ Ot,
                                                _Float16* __restrict__ S3t,
                                                const float* __restrict__ bboxes,
                                                const float* __restrict__ S1,
                                                const float* __restrict__ sb1,
                                                const float* __restrict__ S2,
                                                const float* __restrict__ sb2,
                                                _Float16* __restrict__ h2f,
                                                int2* __restrict__ lst,
                                                int* __restrict__ npA) {
    __shared__ float smem[12 * 256 * 2];   // 24 KB, reused by all branches
    const int bid = blockIdx.x;
    const int t   = threadIdx.x;      // 0..255

    if (bid < kPrepListEnd) {
        // ---- ROI list build + expand: one thread per ROI, weights in LDS ----
        // Thread-major layout: yw[i][t] -> lanes hit distinct banks (t mod 32).
        float* yw = smem;              // [12][256]
        float* xw = smem + 12 * 256;   // [12][256]
        const int r = bid * 256 + t;   // 0..1023
#pragma unroll
        for (int i = 0; i < 12; ++i) { yw[i * 256 + t] = 0.0f; xw[i * 256 + t] = 0.0f; }

        const float x1 = bboxes[r * 4 + 0] * 0.125f - 0.5f;
        const float y1 = bboxes[r * 4 + 1] * 0.125f - 0.5f;
        const float x2 = bboxes[r * 4 + 2] * 0.125f - 0.5f;
        const float y2 = bboxes[r * 4 + 3] * 0.125f - 0.5f;
        const float rw = x2 - x1, rh = y2 - y1;
        const float gwf = fminf(fmaxf(ceilf(rw), 1.0f), 8.0f);
        const float ghf = fminf(fmaxf(ceilf(rh), 1.0f), 8.0f);
        const int gw = (int)gwf, gh = (int)ghf;
        const float ic = 1.0f / (gwf * ghf);

        int ymin = 0, last = 0;
        for (int g = 0; g < gh; ++g) {
            const float c   = y1 + ((float)g + 0.5f) * rh / ghf;
            const bool oob  = (c < -1.0f) || (c > 64.0f);
            const float cc  = fmaxf(c, 0.0f);
            const float lo0 = floorf(cc);
            const bool hic  = (lo0 >= 63.0f);
            const int lo    = (int)fminf(lo0, 63.0f);
            const int hi    = (int)fminf(lo0 + 1.0f, 63.0f);
            const float fr  = hic ? 0.0f : (cc - lo0);
            const float m   = oob ? 0.0f : 1.0f;
            if (g == 0) ymin = lo;
            const int il = min(lo - ymin, 11);
            const int ih = min(hi - ymin, 11);
            yw[il * 256 + t] += m * (1.0f - fr);
            yw[ih * 256 + t] += m * fr;
            last = hi;
        }
        const int nyd = min(last - ymin + 1, 12);

        int xmin = 0; last = 0;
        for (int g = 0; g < gw; ++g) {
            const float c   = x1 + ((float)g + 0.5f) * rw / gwf;
            const bool oob  = (c < -1.0f) || (c > 64.0f);
            const float cc  = fmaxf(c, 0.0f);
            const float lo0 = floorf(cc);
            const bool hic  = (lo0 >= 63.0f);
            const int lo    = (int)fminf(lo0, 63.0f);
            const int hi    = (int)fminf(lo0 + 1.0f, 63.0f);
            const float fr  = hic ? 0.0f : (cc - lo0);
            const float m   = oob ? 0.0f : 1.0f;
            if (g == 0) xmin = lo;
            const int il = min(lo - xmin, 11);
            const int ih = min(hi - xmin, 11);
            xw[il * 256 + t] += m * (1.0f - fr);
            xw[ih * 256 + t] += m * fr;
            last = hi;
        }
        const int nxd = min(last - xmin + 1, 12);

        int2* lr = lst + (size_t)r * kLB;
        int p = 0;
        for (int iy = 0; iy < nyd; ++iy) {
            const float wy = yw[iy * 256 + t] * ic;
            const int yb   = (ymin + iy) * kW + xmin;
            for (int ix = 0; ix < nxd; ++ix) {
                const float w = wy * xw[ix * 256 + t];
                if (w != 0.0f) {
                    int2 e; e.x = yb + ix; e.y = __float_as_int(w);
                    lr[p++] = e;
                }
            }
        }
        npA[r] = p;
    } else if (bid < kPrepMlpEnd) {
        // ---- size-MLP layers 1+2: 2 -> 64 -> 256, 4 rows/block ----
        const int r0 = (bid - kPrepListEnd) * 4;
        float* sz = smem;             // [4][2]
        float* h1 = smem + 8;         // [4][64]
        if (t < 8) {
            const int row = t >> 1;
            const int c   = t & 1;
            const float* bb = bboxes + (size_t)(r0 + row) * 4;
            sz[row * 2 + c] = (c == 0) ? (bb[3] - bb[1]) : (bb[2] - bb[0]);
        }
        __syncthreads();
        {   // layer 1: 4 rows x 64 = 256 items, one per thread
            const int row = t >> 6;
            const int j   = t & 63;
            const float v = sz[row * 2] * S1[j] + sz[row * 2 + 1] * S1[64 + j] + sb1[j];
            h1[row * 64 + j] = fmaxf(v, 0.0f);
        }
        __syncthreads();
        {   // layer 2: j = t, 4 rows register-blocked
            float acc[4];
            const float b = sb2[t];
#pragma unroll
            for (int row = 0; row < 4; ++row) acc[row] = b;
#pragma unroll 16
            for (int k = 0; k < 64; ++k) {
                const float w = S2[k * 256 + t];
#pragma unroll
                for (int row = 0; row < 4; ++row) acc[row] += h1[row * 64 + k] * w;
            }
#pragma unroll
            for (int row = 0; row < 4; ++row)
                h2f[(size_t)(r0 + row) * kE2 + t] = (_Float16)fmaxf(acc[row], 0.0f);
        }
    } else {
        // ---- weight convert+transpose: W (K x N) fp32 -> Wt (N x K) f16 ----
        const int cb = bid - kPrepMlpEnd;
        const float* W; _Float16* Wt; int K, N, tile;
        if (cb < 6400)        { W = W1; Wt = W1t; K = kCH;    N = kINNER; tile = cb; }
        else if (cb < 11520)  { W = W2; Wt = W2t; K = kINNER; N = kOUTC;  tile = cb - 6400; }
        else if (cb < 13568)  { W = O;  Wt = Ot;  K = kXE;    N = kOUTC;  tile = cb - 11520; }
        else                  { W = S3; Wt = S3t; K = kE2;    N = kOUTC;  tile = cb - 13568; }
        const int nt = N / 32;
        const int n0 = (tile % nt) * 32;
        const int k0 = (tile / nt) * 32;
        {   // load 32x32 floats as 256 float4 (row = k-local, col = n-local)
            const int row = t >> 3;          // 0..31
            const int c4  = (t & 7) * 4;     // 0..28
            const float4 v = *(const float4*)&W[(size_t)(k0 + row) * N + n0 + c4];
            float* tl = smem + row * 33 + c4;
            tl[0] = v.x; tl[1] = v.y; tl[2] = v.z; tl[3] = v.w;
        }
        __syncthreads();
        {   // transposed store: 4 k packed per thread -> uint2 (8B)
            const int n  = t >> 3;           // 0..31
            const int k4 = (t & 7) * 4;      // 0..28
            union { _Float16 h[4]; uint2 u; } pk;
#pragma unroll
            for (int j = 0; j < 4; ++j) pk.h[j] = (_Float16)smem[(k4 + j) * 33 + n];
            *(uint2*)&Wt[(size_t)(n0 + n) * K + k0 + k4] = pk.u;
        }
    }
}

// ---------------------------------------------------------------------------
// ROI gather from fp32 z channel planes staged in LDS (verified round 8).
// Block = (channel-group of 4, image). Every z byte read ONCE.
// ---------------------------------------------------------------------------
static constexpr int kPC = 4;       // planes per block
static constexpr int kPS = 4112;    // padded plane stride in floats (16B-aligned)

__global__ __launch_bounds__(256) void roi_gather_planes(const float* __restrict__ z,
                                                         const int2* __restrict__ lst,
                                                         const int* __restrict__ npA,
                                                         _Float16* __restrict__ x) {
    __shared__ float pl[kPC * kPS];   // 64.3 KB
    const int chg = blockIdx.x;       // 0..319
    const int b   = blockIdx.y;       // 0..7
    const int c0  = chg * kPC;
    const int t   = threadIdx.x;
    const float* zb = z + ((size_t)b * kCH + c0) * kPIX;
    // load: 4 planes = 4096 float4, 16 per thread, fully coalesced
#pragma unroll
    for (int i = 0; i < 16; ++i) {
        const int idx = t + i * 256;        // float4 index 0..4095
        const int ch  = idx >> 10;          // 0..3
        const int w4  = (idx & 1023) * 4;   // float offset in plane
        const float4 v = *(const float4*)&zb[(size_t)ch * kPIX + w4];
        *(float4*)&pl[ch * kPS + w4] = v;
    }
    __syncthreads();
    const int ch   = t & 3;
    const int slot = t >> 2;               // 0..63
    const float* plc = pl + ch * kPS;
#pragma unroll
    for (int rr = 0; rr < 2; ++rr) {
        const int r = b * kNROI + slot + rr * 64;
        const int np = npA[r];
        const int2* lr = lst + (size_t)r * kLB;
        float acc = 0.0f;
        for (int p = 0; p < np; ++p) {
            const int2 e = lr[p];
            acc += __int_as_float(e.y) * plc[e.x];
        }
        x[(size_t)r * kCH + c0 + ch] = (_Float16)acc;
    }
}

// ---------------------------------------------------------------------------
// f16 MFMA GEMM (NT), 128x128 tile, BK=32, 256 threads = 4 waves.
// Double-buffered global_load_lds staging (verified rounds 3/5/6/7).
// Split-K partial (blockIdx.z), raw fp32 plane store -> P.
// ---------------------------------------------------------------------------
template <int NSPLIT>
__global__ __launch_bounds__(256) void gemm_f16_sk(const _Float16* __restrict__ A,
                                                   const _Float16* __restrict__ Bt,
                                                   float* __restrict__ P,
                                                   int Kfull) {
    __shared__ _Float16 As[2][128 * 32];
    __shared__ _Float16 Bs[2][128 * 32];
    const int t    = threadIdx.x;
    const int lane = t & 63;
    const int wave = t >> 6;
    const int m0 = blockIdx.y * 128, n0 = blockIdx.x * 128;
    const int Ksplit = Kfull / NSPLIT;
    const int s  = blockIdx.z;
    const int Nn = gridDim.x * 128;
    const int Mm = gridDim.y * 128;

    const int c0 = t, c1 = t + 256;
    const _Float16* Ag0 = A + (size_t)(m0 + (c0 >> 2)) * Kfull + (c0 & 3) * 8 + s * Ksplit;
    const _Float16* Ag1 = A + (size_t)(m0 + (c1 >> 2)) * Kfull + (c1 & 3) * 8 + s * Ksplit;
    const _Float16* Bg0 = Bt + (size_t)(n0 + (c0 >> 2)) * Kfull + (c0 & 3) * 8 + s * Ksplit;
    const _Float16* Bg1 = Bt + (size_t)(n0 + (c1 >> 2)) * Kfull + (c1 & 3) * 8 + s * Ksplit;

    const int wm = (wave >> 1) * 64;
    const int wn = (wave & 1) * 64;
    const int fm = lane & 15;
    const int kq = (lane >> 4) * 8;

    floatx4 acc[4][4];
#pragma unroll
    for (int i = 0; i < 4; ++i)
#pragma unroll
        for (int j = 0; j < 4; ++j) acc[i][j] = (floatx4){0.f, 0.f, 0.f, 0.f};

    const int nsteps = Ksplit / 32;
    gload_lds16(Ag0, &As[0][c0 * 8]);
    gload_lds16(Ag1, &As[0][c1 * 8]);
    gload_lds16(Bg0, &Bs[0][c0 * 8]);
    gload_lds16(Bg1, &Bs[0][c1 * 8]);
    __syncthreads();

    for (int ks = 0; ks < nsteps; ++ks) {
        const int cur = ks & 1;
        if (ks + 1 < nsteps) {
            const int kn = (ks + 1) * 32;
            gload_lds16(Ag0 + kn, &As[cur ^ 1][c0 * 8]);
            gload_lds16(Ag1 + kn, &As[cur ^ 1][c1 * 8]);
            gload_lds16(Bg0 + kn, &Bs[cur ^ 1][c0 * 8]);
            gload_lds16(Bg1 + kn, &Bs[cur ^ 1][c1 * 8]);
        }
        half8 af[4], bfv[4];
#pragma unroll
        for (int i = 0; i < 4; ++i)
            af[i] = *(const half8*)&As[cur][(wm + i * 16 + fm) * 32 + kq];
#pragma unroll
        for (int j = 0; j < 4; ++j)
            bfv[j] = *(const half8*)&Bs[cur][(wn + j * 16 + fm) * 32 + kq];
#pragma unroll
        for (int i = 0; i < 4; ++i)
#pragma unroll
            for (int j = 0; j < 4; ++j)
                acc[i][j] = __builtin_amdgcn_mfma_f32_16x16x32_f16(af[i], bfv[j], acc[i][j], 0, 0, 0);
        __syncthreads();
    }

    float* Pp = P + (size_t)s * Mm * Nn;
    const int qr = (lane >> 4) * 4;
#pragma unroll
    for (int j = 0; j < 4; ++j) {
        const int col = n0 + wn + j * 16 + fm;
#pragma unroll
        for (int i = 0; i < 4; ++i) {
            const int row = m0 + wm + i * 16 + qr;
#pragma unroll
            for (int rr = 0; rr < 4; ++rr)
                Pp[(size_t)(row + rr) * Nn + col] = acc[i][j][rr];
        }
    }
}

// ---------------------------------------------------------------------------
// DUAL fused GEMM: S3-embedding GEMM (64 blocks) + GEMM1 (320 blocks) in one
// launch (verified rounds 6/7/8).
// ---------------------------------------------------------------------------
__global__ __launch_bounds__(256) void gemm_dual(const _Float16* __restrict__ h2f,
                                                 const _Float16* __restrict__ S3t,
                                                 const float* __restrict__ sb3,
                                                 _Float16* __restrict__ xeR,
                                                 const _Float16* __restrict__ x,
                                                 const _Float16* __restrict__ W1t,
                                                 const float* __restrict__ b1,
                                                 _Float16* __restrict__ h) {
    __shared__ _Float16 As[2][128 * 32];
    __shared__ _Float16 Bs[2][128 * 32];
    const int bid = blockIdx.x;
    const _Float16* A; const _Float16* Bt; const float* bias; _Float16* Out;
    int Kfull, ldc, nbn, tile; bool relu;
    if (bid < 64) {
        A = h2f; Bt = S3t; bias = sb3; Out = xeR;
        Kfull = kE2; ldc = kXE; relu = false; nbn = kOUTC / 128; tile = bid;
    } else {
        A = x; Bt = W1t; bias = b1; Out = h;
        Kfull = kCH; ldc = kINNER; relu = true; nbn = kINNER / 128; tile = bid - 64;
    }
    const int n0 = (tile % nbn) * 128;
    const int m0 = (tile / nbn) * 128;

    const int t    = threadIdx.x;
    const int lane = t & 63;
    const int wave = t >> 6;

    const int c0 = t, c1 = t + 256;
    const _Float16* Ag0 = A + (size_t)(m0 + (c0 >> 2)) * Kfull + (c0 & 3) * 8;
    const _Float16* Ag1 = A + (size_t)(m0 + (c1 >> 2)) * Kfull + (c1 & 3) * 8;
    const _Float16* Bg0 = Bt + (size_t)(n0 + (c0 >> 2)) * Kfull + (c0 & 3) * 8;
    const _Float16* Bg1 = Bt + (size_t)(n0 + (c1 >> 2)) * Kfull + (c1 & 3) * 8;

    const int wm = (wave >> 1) * 64;
    const int wn = (wave & 1) * 64;
    const int fm = lane & 15;
    const int kq = (lane >> 4) * 8;

    floatx4 acc[4][4];
#pragma unroll
    for (int i = 0; i < 4; ++i)
#pragma unroll
        for (int j = 0; j < 4; ++j) acc[i][j] = (floatx4){0.f, 0.f, 0.f, 0.f};

    const int nsteps = Kfull / 32;
    gload_lds16(Ag0, &As[0][c0 * 8]);
    gload_lds16(Ag1, &As[0][c1 * 8]);
    gload_lds16(Bg0, &Bs[0][c0 * 8]);
    gload_lds16(Bg1, &Bs[0][c1 * 8]);
    __syncthreads();

    for (int ks = 0; ks < nsteps; ++ks) {
        const int cur = ks & 1;
        if (ks + 1 < nsteps) {
            const int kn = (ks + 1) * 32;
            gload_lds16(Ag0 + kn, &As[cur ^ 1][c0 * 8]);
            gload_lds16(Ag1 + kn, &As[cur ^ 1][c1 * 8]);
            gload_lds16(Bg0 + kn, &Bs[cur ^ 1][c0 * 8]);
            gload_lds16(Bg1 + kn, &Bs[cur ^ 1][c1 * 8]);
        }
        half8 af[4], bfv[4];
#pragma unroll
        for (int i = 0; i < 4; ++i)
            af[i] = *(const half8*)&As[cur][(wm + i * 16 + fm) * 32 + kq];
#pragma unroll
        for (int j = 0; j < 4; ++j)
            bfv[j] = *(const half8*)&Bs[cur][(wn + j * 16 + fm) * 32 + kq];
#pragma unroll
        for (int i = 0; i < 4; ++i)
#pragma unroll
            for (int j = 0; j < 4; ++j)
                acc[i][j] = __builtin_amdgcn_mfma_f32_16x16x32_f16(af[i], bfv[j], acc[i][j], 0, 0, 0);
        __syncthreads();
    }

    // Epilogue: bias (+relu) -> f16 at ldc. C/D: col = lane&15, row = (lane>>4)*4+rr
    const int qr = (lane >> 4) * 4;
#pragma unroll
    for (int j = 0; j < 4; ++j) {
        const int col = n0 + wn + j * 16 + fm;
        const float bv = bias[col];
#pragma unroll
        for (int i = 0; i < 4; ++i) {
            const int row = m0 + wm + i * 16 + qr;
#pragma unroll
            for (int rr = 0; rr < 4; ++rr) {
                float v = acc[i][j][rr] + bv;
                if (relu) v = fmaxf(v, 0.f);
                Out[(size_t)(row + rr) * ldc + col] = (_Float16)v;
            }
        }
    }
}

// ---------------------------------------------------------------------------
// Split-K reduce + bias + (relu) + convert.
// ---------------------------------------------------------------------------
template <bool RELU, bool F16OUT, int NSPLIT>
__global__ __launch_bounds__(256) void reduce_splitk(const float* __restrict__ P,
                                                     const float* __restrict__ bias,
                                                     void* __restrict__ Cout,
                                                     int Nn, int ldc) {
    const size_t idx = ((size_t)blockIdx.x * 256 + threadIdx.x) * 4;
    const size_t MN  = (size_t)gridDim.x * 1024;
    const int m = (int)(idx / (size_t)Nn);
    const int n = (int)(idx % (size_t)Nn);
    float4 acc = *(const float4*)(P + idx);
#pragma unroll
    for (int s = 1; s < NSPLIT; ++s) {
        const float4 v = *(const float4*)(P + (size_t)s * MN + idx);
        acc.x += v.x; acc.y += v.y; acc.z += v.z; acc.w += v.w;
    }
    const float4 b4 = *(const float4*)(bias + n);
    acc.x += b4.x; acc.y += b4.y; acc.z += b4.z; acc.w += b4.w;
    if (RELU) {
        acc.x = fmaxf(acc.x, 0.f); acc.y = fmaxf(acc.y, 0.f);
        acc.z = fmaxf(acc.z, 0.f); acc.w = fmaxf(acc.w, 0.f);
    }
    if (F16OUT) {
        union { _Float16 h[4]; uint2 u; } pk;
        pk.h[0] = (_Float16)acc.x; pk.h[1] = (_Float16)acc.y;
        pk.h[2] = (_Float16)acc.z; pk.h[3] = (_Float16)acc.w;
        *(uint2*)((_Float16*)Cout + (size_t)m * ldc + n) = pk.u;
    } else {
        *(float4*)((float*)Cout + (size_t)m * ldc + n) = acc;
    }
}

// ---------------------------------------------------------------------------
extern "C" void kernel_launch(void* const* d_in, const int* in_sizes, int n_in,
                              void* d_out, int out_size, void* d_ws, size_t ws_size,
                              hipStream_t stream) {
    (void)in_sizes; (void)n_in; (void)out_size; (void)ws_size;
    const float* z   = (const float*)d_in[0];
    const float* bb  = (const float*)d_in[1];
    const float* W1  = (const float*)d_in[2];
    const float* b1  = (const float*)d_in[3];
    const float* W2  = (const float*)d_in[4];
    const float* b2  = (const float*)d_in[5];
    const float* S1  = (const float*)d_in[6];
    const float* sb1 = (const float*)d_in[7];
    const float* S2  = (const float*)d_in[8];
    const float* sb2 = (const float*)d_in[9];
    const float* S3  = (const float*)d_in[10];
    const float* sb3 = (const float*)d_in[11];
    const float* O   = (const float*)d_in[12];
    const float* ob  = (const float*)d_in[13];
    float* out = (float*)d_out;

    char* ws = (char*)d_ws;
    size_t off = 0;
    auto alloc = [&](size_t bytes) {
        void* p = ws + off;
        off += (bytes + 255) & ~(size_t)255;
        return p;
    };
    _Float16* x    = (_Float16*)alloc((size_t)kR * kCH * 2);        //  2.6 MB
    _Float16* h    = (_Float16*)alloc((size_t)kR * kINNER * 2);     // 10.5 MB
    _Float16* xe   = (_Float16*)alloc((size_t)kR * kXE * 2);        //  4.2 MB
    _Float16* W1t  = (_Float16*)alloc((size_t)kINNER * kCH * 2);    // 13.1 MB
    _Float16* W2t  = (_Float16*)alloc((size_t)kOUTC * kINNER * 2);  // 10.5 MB
    _Float16* Ot   = (_Float16*)alloc((size_t)kOUTC * kXE * 2);     //  4.2 MB
    _Float16* S3t  = (_Float16*)alloc((size_t)kOUTC * kE2 * 2);     //  0.5 MB
    _Float16* h2f  = (_Float16*)alloc((size_t)kR * kE2 * 2);        //  0.5 MB
    int2*     lst  = (int2*)alloc((size_t)kR * kLB * 8);            //  1.2 MB
    int*      npA  = (int*)alloc((size_t)kR * 4);                   //  4 KB
    float*    P    = (float*)alloc((size_t)8 * kR * kOUTC * 4);     // 33.6 MB

    // 0) all prep (ROI lists + size-MLP 1+2 + weight converts) in one launch
    hipLaunchKernelGGL(prep_all, dim3(kPrepAllEnd), dim3(256), 0, stream,
                       W1, W2, O, S3, W1t, W2t, Ot, S3t,
                       bb, S1, sb1, S2, sb2, h2f, lst, npA);

    // 1) ROI-align features from fp32 z planes -> x (1024 x 1280 f16)
    hipLaunchKernelGGL(roi_gather_planes, dim3(kCH / kPC, kBS), dim3(256), 0, stream,
                       z, lst, npA, x);

    // 2) dual fused GEMM: S3-embedding (64 blocks) + GEMM1 (320 blocks)
    hipLaunchKernelGGL(gemm_dual, dim3(64 + (kINNER / 128) * (kR / 128)), dim3(256), 0,
                       stream, h2f, S3t, sb3, xe + kOUTC, x, W1t, b1, h);

    // 3) xe[:, 0:1024] = h @ W2 + b2: split-K x8 (512 blocks = 2/CU, 20 k-steps)
    hipLaunchKernelGGL((gemm_f16_sk<8>), dim3(kOUTC / 128, kR / 128, 8), dim3(256), 0,
                       stream, h, W2t, P, kINNER);
    hipLaunchKernelGGL((reduce_splitk<false, true, 8>),
                       dim3((size_t)kR * kOUTC / 1024), dim3(256), 0, stream,
                       P, b2, xe, kOUTC, kXE);

    // 4) out = xe @ O + ob: split-K x8 (512 blocks = 2/CU, 8 k-steps)
    hipLaunchKernelGGL((gemm_f16_sk<8>), dim3(kOUTC / 128, kR / 128, 8), dim3(256), 0,
                       stream, xe, Ot, P, kXE);
    hipLaunchKernelGGL((reduce_splitk<false, false, 8>),
                       dim3((size_t)kR * kOUTC / 1024), dim3(256), 0, stream,
                       P, ob, out, kOUTC, kOUTC);
}

// Round 10
// 397.951 us; speedup vs baseline: 1.0983x; 1.0224x over previous
//
#include <hip/hip_runtime.h>

// Problem constants
static constexpr int kBS    = 8;
static constexpr int kNROI  = 128;
static constexpr int kR     = kBS * kNROI;   // 1024 rows
static constexpr int kCH    = 1280;
static constexpr int kH     = 64;
static constexpr int kW     = 64;
static constexpr int kPIX   = kH * kW;       // 4096
static constexpr int kINNER = 5120;
static constexpr int kOUTC  = 1024;
static constexpr int kXE    = 2 * kOUTC;     // 2048 concat width
static constexpr int kE2    = 256;           // size-MLP hidden 2

typedef _Float16 half8 __attribute__((ext_vector_type(8)));   // f16x8 MFMA A/B frag
typedef float floatx4 __attribute__((ext_vector_type(4)));    // MFMA C/D frag

// Async global->LDS 16B copy. LDS dest must be wave-uniform base + lane*16,
// which our chunk-index==threadIdx staging layout satisfies exactly.
__device__ __forceinline__ void gload_lds16(const _Float16* g, _Float16* l) {
    __builtin_amdgcn_global_load_lds(
        (const __attribute__((address_space(1))) void*)g,
        (__attribute__((address_space(3))) void*)l,
        16, 0, 0);
}

// ---------------------------------------------------------------------------
// FRONT mega-kernel: ROI gather (self-contained) + size-MLP 1+2 + weight
// converts, all in ONE launch. Gather blocks are latency-bound and BW-light;
// conv blocks are BW-bound and latency-light -> co-scheduling overlaps them.
// Flat 256 threads. Block ranges:
//   [0, 5120)       : gather; block = (2-channel group, image). Stages 2
//                     fp32 z planes in LDS, builds all 128 ROI lists of its
//                     image in LDS (R9-verified math), gathers 2ch x 128 ROI.
//   [5120, 5376)    : size-MLP layers 1+2 (4 ROIs per block)
//   [5376, 19200)   : weight transpose+convert 32x32 tiles (W1, W2, O, S3)
// ---------------------------------------------------------------------------
static constexpr int kPC = 2;       // planes per gather block
static constexpr int kPS = 4100;    // padded plane stride in floats (16B-aligned;
                                    // 4100 % 32 = 4 -> ch pair hits distinct banks)
static constexpr int kFGat = (kCH / kPC) * kBS;   // 5120
static constexpr int kFMlp = kFGat + 256;         // 5376
static constexpr int kFAll = kFMlp + 13824;       // 19200

__global__ __launch_bounds__(256) void front_all(const float* __restrict__ z,
                                                 const float* __restrict__ bboxes,
                                                 const float* __restrict__ W1,
                                                 const float* __restrict__ W2,
                                                 const float* __restrict__ O,
                                                 const float* __restrict__ S3,
                                                 _Float16* __restrict__ W1t,
                                                 _Float16* __restrict__ W2t,
                                                 _Float16* __restrict__ Ot,
                                                 _Float16* __restrict__ S3t,
                                                 const float* __restrict__ S1,
                                                 const float* __restrict__ sb1,
                                                 const float* __restrict__ S2,
                                                 const float* __restrict__ sb2,
                                                 _Float16* __restrict__ h2f,
                                                 _Float16* __restrict__ x) {
    // Gather layout: planes [2][4100] | ywL [12][128] | xwL [12][128] | meta [4][128]
    __shared__ float smem[kPC * kPS + 12 * 128 + 12 * 128 + 512];   // 47.1 KB
    const int bid = blockIdx.x;
    const int t   = threadIdx.x;      // 0..255

    if (bid < kFGat) {
        // ---- ROI gather from fp32 z planes (every z byte read ONCE) ----
        float* pl  = smem;                       // [2][kPS]
        float* ywL = smem + kPC * kPS;           // [12][128] (ic folded in)
        float* xwL = ywL + 12 * 128;             // [12][128]
        int*   im  = (int*)(xwL + 12 * 128);     // ymin|xmin|nyd|nxd, 128 each
        const int b   = bid & 7;
        const int chg = bid >> 3;                // 0..639
        const int c0  = chg * kPC;
        const float* zb = z + ((size_t)b * kCH + c0) * kPIX;
        // stage 2 planes: 2048 float4, 8 per thread, fully coalesced
#pragma unroll
        for (int i = 0; i < 8; ++i) {
            const int idx = t + i * 256;        // float4 index 0..2047
            const int ch  = idx >> 10;          // 0..1
            const int w4  = (idx & 1023) * 4;   // float offset in plane
            const float4 v = *(const float4*)&zb[(size_t)ch * kPIX + w4];
            *(float4*)&pl[ch * kPS + w4] = v;
        }
        // build consolidated weight lists for all 128 ROIs of image b
        if (t < 128) {
            const int r = b * kNROI + t;
#pragma unroll
            for (int i = 0; i < 12; ++i) { ywL[i * 128 + t] = 0.0f; xwL[i * 128 + t] = 0.0f; }
            const float x1 = bboxes[r * 4 + 0] * 0.125f - 0.5f;
            const float y1 = bboxes[r * 4 + 1] * 0.125f - 0.5f;
            const float x2 = bboxes[r * 4 + 2] * 0.125f - 0.5f;
            const float y2 = bboxes[r * 4 + 3] * 0.125f - 0.5f;
            const float rw = x2 - x1, rh = y2 - y1;
            const float gwf = fminf(fmaxf(ceilf(rw), 1.0f), 8.0f);
            const float ghf = fminf(fmaxf(ceilf(rh), 1.0f), 8.0f);
            const int gw = (int)gwf, gh = (int)ghf;
            const float ic = 1.0f / (gwf * ghf);

            int ymin = 0, last = 0;
            for (int g = 0; g < gh; ++g) {
                const float c   = y1 + ((float)g + 0.5f) * rh / ghf;
                const bool oob  = (c < -1.0f) || (c > 64.0f);
                const float cc  = fmaxf(c, 0.0f);
                const float lo0 = floorf(cc);
                const bool hic  = (lo0 >= 63.0f);
                const int lo    = (int)fminf(lo0, 63.0f);
                const int hi    = (int)fminf(lo0 + 1.0f, 63.0f);
                const float fr  = hic ? 0.0f : (cc - lo0);
                const float m   = oob ? 0.0f : 1.0f;
                if (g == 0) ymin = lo;
                const int il = min(lo - ymin, 11);
                const int ih = min(hi - ymin, 11);
                ywL[il * 128 + t] += m * (1.0f - fr);
                ywL[ih * 128 + t] += m * fr;
                last = hi;
            }
            const int nyd = min(last - ymin + 1, 12);

            int xmin = 0; last = 0;
            for (int g = 0; g < gw; ++g) {
                const float c   = x1 + ((float)g + 0.5f) * rw / gwf;
                const bool oob  = (c < -1.0f) || (c > 64.0f);
                const float cc  = fmaxf(c, 0.0f);
                const float lo0 = floorf(cc);
                const bool hic  = (lo0 >= 63.0f);
                const int lo    = (int)fminf(lo0, 63.0f);
                const int hi    = (int)fminf(lo0 + 1.0f, 63.0f);
                const float fr  = hic ? 0.0f : (cc - lo0);
                const float m   = oob ? 0.0f : 1.0f;
                if (g == 0) xmin = lo;
                const int il = min(lo - xmin, 11);
                const int ih = min(hi - xmin, 11);
                xwL[il * 128 + t] += m * (1.0f - fr);
                xwL[ih * 128 + t] += m * fr;
                last = hi;
            }
            const int nxd = min(last - xmin + 1, 12);
#pragma unroll
            for (int i = 0; i < 12; ++i) ywL[i * 128 + t] *= ic;   // fold invCount
            im[t] = ymin; im[128 + t] = xmin; im[256 + t] = nyd; im[384 + t] = nxd;
        }
        __syncthreads();
        // gather: thread = (ch = t&1, ROI = t>>1); weights from LDS
        const int ch = t & 1;
        const int ri = t >> 1;                 // 0..127
        const int r  = b * kNROI + ri;
        const float* plc = pl + ch * kPS;
        const int ym = im[ri], xm = im[128 + ri];
        const int ny = im[256 + ri], nx = im[384 + ri];
        float acc = 0.0f;
        for (int iy = 0; iy < ny; ++iy) {
            const float wy = ywL[iy * 128 + ri];
            const int ro   = (ym + iy) * kW + xm;
            for (int ix = 0; ix < nx; ++ix)
                acc += wy * xwL[ix * 128 + ri] * plc[ro + ix];
        }
        x[(size_t)r * kCH + c0 + ch] = (_Float16)acc;
    } else if (bid < kFMlp) {
        // ---- size-MLP layers 1+2: 2 -> 64 -> 256, 4 rows/block ----
        const int r0 = (bid - kFGat) * 4;
        float* sz = smem;             // [4][2]
        float* h1 = smem + 8;         // [4][64]
        if (t < 8) {
            const int row = t >> 1;
            const int c   = t & 1;
            const float* bb = bboxes + (size_t)(r0 + row) * 4;
            sz[row * 2 + c] = (c == 0) ? (bb[3] - bb[1]) : (bb[2] - bb[0]);
        }
        __syncthreads();
        {   // layer 1: 4 rows x 64 = 256 items, one per thread
            const int row = t >> 6;
            const int j   = t & 63;
            const float v = sz[row * 2] * S1[j] + sz[row * 2 + 1] * S1[64 + j] + sb1[j];
            h1[row * 64 + j] = fmaxf(v, 0.0f);
        }
        __syncthreads();
        {   // layer 2: j = t, 4 rows register-blocked
            float acc[4];
            const float b = sb2[t];
#pragma unroll
            for (int row = 0; row < 4; ++row) acc[row] = b;
#pragma unroll 16
            for (int k = 0; k < 64; ++k) {
                const float w = S2[k * 256 + t];
#pragma unroll
                for (int row = 0; row < 4; ++row) acc[row] += h1[row * 64 + k] * w;
            }
#pragma unroll
            for (int row = 0; row < 4; ++row)
                h2f[(size_t)(r0 + row) * kE2 + t] = (_Float16)fmaxf(acc[row], 0.0f);
        }
    } else {
        // ---- weight convert+transpose: W (K x N) fp32 -> Wt (N x K) f16 ----
        const int cb = bid - kFMlp;
        const float* W; _Float16* Wt; int K, N, tile;
        if (cb < 6400)        { W = W1; Wt = W1t; K = kCH;    N = kINNER; tile = cb; }
        else if (cb < 11520)  { W = W2; Wt = W2t; K = kINNER; N = kOUTC;  tile = cb - 6400; }
        else if (cb < 13568)  { W = O;  Wt = Ot;  K = kXE;    N = kOUTC;  tile = cb - 11520; }
        else                  { W = S3; Wt = S3t; K = kE2;    N = kOUTC;  tile = cb - 13568; }
        const int nt = N / 32;
        const int n0 = (tile % nt) * 32;
        const int k0 = (tile / nt) * 32;
        {   // load 32x32 floats as 256 float4 (row = k-local, col = n-local)
            const int row = t >> 3;          // 0..31
            const int c4  = (t & 7) * 4;     // 0..28
            const float4 v = *(const float4*)&W[(size_t)(k0 + row) * N + n0 + c4];
            float* tl = smem + row * 33 + c4;
            tl[0] = v.x; tl[1] = v.y; tl[2] = v.z; tl[3] = v.w;
        }
        __syncthreads();
        {   // transposed store: 4 k packed per thread -> uint2 (8B)
            const int n  = t >> 3;           // 0..31
            const int k4 = (t & 7) * 4;      // 0..28
            union { _Float16 h[4]; uint2 u; } pk;
#pragma unroll
            for (int j = 0; j < 4; ++j) pk.h[j] = (_Float16)smem[(k4 + j) * 33 + n];
            *(uint2*)&Wt[(size_t)(n0 + n) * K + k0 + k4] = pk.u;
        }
    }
}

// ---------------------------------------------------------------------------
// f16 MFMA GEMM (NT), 128x128 tile, BK=32, 256 threads = 4 waves.
// Double-buffered global_load_lds staging (verified rounds 3/5/6/7/9).
// Split-K partial (blockIdx.z), raw fp32 plane store -> P.
// ---------------------------------------------------------------------------
template <int NSPLIT>
__global__ __launch_bounds__(256) void gemm_f16_sk(const _Float16* __restrict__ A,
                                                   const _Float16* __restrict__ Bt,
                                                   float* __restrict__ P,
                                                   int Kfull) {
    __shared__ _Float16 As[2][128 * 32];
    __shared__ _Float16 Bs[2][128 * 32];
    const int t    = threadIdx.x;
    const int lane = t & 63;
    const int wave = t >> 6;
    const int m0 = blockIdx.y * 128, n0 = blockIdx.x * 128;
    const int Ksplit = Kfull / NSPLIT;
    const int s  = blockIdx.z;
    const int Nn = gridDim.x * 128;
    const int Mm = gridDim.y * 128;

    const int c0 = t, c1 = t + 256;
    const _Float16* Ag0 = A + (size_t)(m0 + (c0 >> 2)) * Kfull + (c0 & 3) * 8 + s * Ksplit;
    const _Float16* Ag1 = A + (size_t)(m0 + (c1 >> 2)) * Kfull + (c1 & 3) * 8 + s * Ksplit;
    const _Float16* Bg0 = Bt + (size_t)(n0 + (c0 >> 2)) * Kfull + (c0 & 3) * 8 + s * Ksplit;
    const _Float16* Bg1 = Bt + (size_t)(n0 + (c1 >> 2)) * Kfull + (c1 & 3) * 8 + s * Ksplit;

    const int wm = (wave >> 1) * 64;
    const int wn = (wave & 1) * 64;
    const int fm = lane & 15;
    const int kq = (lane >> 4) * 8;

    floatx4 acc[4][4];
#pragma unroll
    for (int i = 0; i < 4; ++i)
#pragma unroll
        for (int j = 0; j < 4; ++j) acc[i][j] = (floatx4){0.f, 0.f, 0.f, 0.f};

    const int nsteps = Ksplit / 32;
    gload_lds16(Ag0, &As[0][c0 * 8]);
    gload_lds16(Ag1, &As[0][c1 * 8]);
    gload_lds16(Bg0, &Bs[0][c0 * 8]);
    gload_lds16(Bg1, &Bs[0][c1 * 8]);
    __syncthreads();

    for (int ks = 0; ks < nsteps; ++ks) {
        const int cur = ks & 1;
        if (ks + 1 < nsteps) {
            const int kn = (ks + 1) * 32;
            gload_lds16(Ag0 + kn, &As[cur ^ 1][c0 * 8]);
            gload_lds16(Ag1 + kn, &As[cur ^ 1][c1 * 8]);
            gload_lds16(Bg0 + kn, &Bs[cur ^ 1][c0 * 8]);
            gload_lds16(Bg1 + kn, &Bs[cur ^ 1][c1 * 8]);
        }
        half8 af[4], bfv[4];
#pragma unroll
        for (int i = 0; i < 4; ++i)
            af[i] = *(const half8*)&As[cur][(wm + i * 16 + fm) * 32 + kq];
#pragma unroll
        for (int j = 0; j < 4; ++j)
            bfv[j] = *(const half8*)&Bs[cur][(wn + j * 16 + fm) * 32 + kq];
#pragma unroll
        for (int i = 0; i < 4; ++i)
#pragma unroll
            for (int j = 0; j < 4; ++j)
                acc[i][j] = __builtin_amdgcn_mfma_f32_16x16x32_f16(af[i], bfv[j], acc[i][j], 0, 0, 0);
        __syncthreads();
    }

    float* Pp = P + (size_t)s * Mm * Nn;
    const int qr = (lane >> 4) * 4;
#pragma unroll
    for (int j = 0; j < 4; ++j) {
        const int col = n0 + wn + j * 16 + fm;
#pragma unroll
        for (int i = 0; i < 4; ++i) {
            const int row = m0 + wm + i * 16 + qr;
#pragma unroll
            for (int rr = 0; rr < 4; ++rr)
                Pp[(size_t)(row + rr) * Nn + col] = acc[i][j][rr];
        }
    }
}

// ---------------------------------------------------------------------------
// DUAL fused GEMM: S3-embedding GEMM (64 blocks) + GEMM1 (320 blocks) in one
// launch (verified rounds 6/7/8/9).
// ---------------------------------------------------------------------------
__global__ __launch_bounds__(256) void gemm_dual(const _Float16* __restrict__ h2f,
                                                 const _Float16* __restrict__ S3t,
                                                 const float* __restrict__ sb3,
                                                 _Float16* __restrict__ xeR,
                                                 const _Float16* __restrict__ x,
                                                 const _Float16* __restrict__ W1t,
                                                 const float* __restrict__ b1,
                                                 _Float16* __restrict__ h) {
    __shared__ _Float16 As[2][128 * 32];
    __shared__ _Float16 Bs[2][128 * 32];
    const int bid = blockIdx.x;
    const _Float16* A; const _Float16* Bt; const float* bias; _Float16* Out;
    int Kfull, ldc, nbn, tile; bool relu;
    if (bid < 64) {
        A = h2f; Bt = S3t; bias = sb3; Out = xeR;
        Kfull = kE2; ldc = kXE; relu = false; nbn = kOUTC / 128; tile = bid;
    } else {
        A = x; Bt = W1t; bias = b1; Out = h;
        Kfull = kCH; ldc = kINNER; relu = true; nbn = kINNER / 128; tile = bid - 64;
    }
    const int n0 = (tile % nbn) * 128;
    const int m0 = (tile / nbn) * 128;

    const int t    = threadIdx.x;
    const int lane = t & 63;
    const int wave = t >> 6;

    const int c0 = t, c1 = t + 256;
    const _Float16* Ag0 = A + (size_t)(m0 + (c0 >> 2)) * Kfull + (c0 & 3) * 8;
    const _Float16* Ag1 = A + (size_t)(m0 + (c1 >> 2)) * Kfull + (c1 & 3) * 8;
    const _Float16* Bg0 = Bt + (size_t)(n0 + (c0 >> 2)) * Kfull + (c0 & 3) * 8;
    const _Float16* Bg1 = Bt + (size_t)(n0 + (c1 >> 2)) * Kfull + (c1 & 3) * 8;

    const int wm = (wave >> 1) * 64;
    const int wn = (wave & 1) * 64;
    const int fm = lane & 15;
    const int kq = (lane >> 4) * 8;

    floatx4 acc[4][4];
#pragma unroll
    for (int i = 0; i < 4; ++i)
#pragma unroll
        for (int j = 0; j < 4; ++j) acc[i][j] = (floatx4){0.f, 0.f, 0.f, 0.f};

    const int nsteps = Kfull / 32;
    gload_lds16(Ag0, &As[0][c0 * 8]);
    gload_lds16(Ag1, &As[0][c1 * 8]);
    gload_lds16(Bg0, &Bs[0][c0 * 8]);
    gload_lds16(Bg1, &Bs[0][c1 * 8]);
    __syncthreads();

    for (int ks = 0; ks < nsteps; ++ks) {
        const int cur = ks & 1;
        if (ks + 1 < nsteps) {
            const int kn = (ks + 1) * 32;
            gload_lds16(Ag0 + kn, &As[cur ^ 1][c0 * 8]);
            gload_lds16(Ag1 + kn, &As[cur ^ 1][c1 * 8]);
            gload_lds16(Bg0 + kn, &Bs[cur ^ 1][c0 * 8]);
            gload_lds16(Bg1 + kn, &Bs[cur ^ 1][c1 * 8]);
        }
        half8 af[4], bfv[4];
#pragma unroll
        for (int i = 0; i < 4; ++i)
            af[i] = *(const half8*)&As[cur][(wm + i * 16 + fm) * 32 + kq];
#pragma unroll
        for (int j = 0; j < 4; ++j)
            bfv[j] = *(const half8*)&Bs[cur][(wn + j * 16 + fm) * 32 + kq];
#pragma unroll
        for (int i = 0; i < 4; ++i)
#pragma unroll
            for (int j = 0; j < 4; ++j)
                acc[i][j] = __builtin_amdgcn_mfma_f32_16x16x32_f16(af[i], bfv[j], acc[i][j], 0, 0, 0);
        __syncthreads();
    }

    // Epilogue: bias (+relu) -> f16 at ldc. C/D: col = lane&15, row = (lane>>4)*4+rr
    const int qr = (lane >> 4) * 4;
#pragma unroll
    for (int j = 0; j < 4; ++j) {
        const int col = n0 + wn + j * 16 + fm;
        const float bv = bias[col];
#pragma unroll
        for (int i = 0; i < 4; ++i) {
            const int row = m0 + wm + i * 16 + qr;
#pragma unroll
            for (int rr = 0; rr < 4; ++rr) {
                float v = acc[i][j][rr] + bv;
                if (relu) v = fmaxf(v, 0.f);
                Out[(size_t)(row + rr) * ldc + col] = (_Float16)v;
            }
        }
    }
}

// ---------------------------------------------------------------------------
// Split-K reduce + bias + (relu) + convert.
// ---------------------------------------------------------------------------
template <bool RELU, bool F16OUT, int NSPLIT>
__global__ __launch_bounds__(256) void reduce_splitk(const float* __restrict__ P,
                                                     const float* __restrict__ bias,
                                                     void* __restrict__ Cout,
                                                     int Nn, int ldc) {
    const size_t idx = ((size_t)blockIdx.x * 256 + threadIdx.x) * 4;
    const size_t MN  = (size_t)gridDim.x * 1024;
    const int m = (int)(idx / (size_t)Nn);
    const int n = (int)(idx % (size_t)Nn);
    float4 acc = *(const float4*)(P + idx);
#pragma unroll
    for (int s = 1; s < NSPLIT; ++s) {
        const float4 v = *(const float4*)(P + (size_t)s * MN + idx);
        acc.x += v.x; acc.y += v.y; acc.z += v.z; acc.w += v.w;
    }
    const float4 b4 = *(const float4*)(bias + n);
    acc.x += b4.x; acc.y += b4.y; acc.z += b4.z; acc.w += b4.w;
    if (RELU) {
        acc.x = fmaxf(acc.x, 0.f); acc.y = fmaxf(acc.y, 0.f);
        acc.z = fmaxf(acc.z, 0.f); acc.w = fmaxf(acc.w, 0.f);
    }
    if (F16OUT) {
        union { _Float16 h[4]; uint2 u; } pk;
        pk.h[0] = (_Float16)acc.x; pk.h[1] = (_Float16)acc.y;
        pk.h[2] = (_Float16)acc.z; pk.h[3] = (_Float16)acc.w;
        *(uint2*)((_Float16*)Cout + (size_t)m * ldc + n) = pk.u;
    } else {
        *(float4*)((float*)Cout + (size_t)m * ldc + n) = acc;
    }
}

// ---------------------------------------------------------------------------
extern "C" void kernel_launch(void* const* d_in, const int* in_sizes, int n_in,
                              void* d_out, int out_size, void* d_ws, size_t ws_size,
                              hipStream_t stream) {
    (void)in_sizes; (void)n_in; (void)out_size; (void)ws_size;
    const float* z   = (const float*)d_in[0];
    const float* bb  = (const float*)d_in[1];
    const float* W1  = (const float*)d_in[2];
    const float* b1  = (const float*)d_in[3];
    const float* W2  = (const float*)d_in[4];
    const float* b2  = (const float*)d_in[5];
    const float* S1  = (const float*)d_in[6];
    const float* sb1 = (const float*)d_in[7];
    const float* S2  = (const float*)d_in[8];
    const float* sb2 = (const float*)d_in[9];
    const float* S3  = (const float*)d_in[10];
    const float* sb3 = (const float*)d_in[11];
    const float* O   = (const float*)d_in[12];
    const float* ob  = (const float*)d_in[13];
    float* out = (float*)d_out;

    char* ws = (char*)d_ws;
    size_t off = 0;
    auto alloc = [&](size_t bytes) {
        void* p = ws + off;
        off += (bytes + 255) & ~(size_t)255;
        return p;
    };
    _Float16* x    = (_Float16*)alloc((size_t)kR * kCH * 2);        //  2.6 MB
    _Float16* h    = (_Float16*)alloc((size_t)kR * kINNER * 2);     // 10.5 MB
    _Float16* xe   = (_Float16*)alloc((size_t)kR * kXE * 2);        //  4.2 MB
    _Float16* W1t  = (_Float16*)alloc((size_t)kINNER * kCH * 2);    // 13.1 MB
    _Float16* W2t  = (_Float16*)alloc((size_t)kOUTC * kINNER * 2);  // 10.5 MB
    _Float16* Ot   = (_Float16*)alloc((size_t)kOUTC * kXE * 2);     //  4.2 MB
    _Float16* S3t  = (_Float16*)alloc((size_t)kOUTC * kE2 * 2);     //  0.5 MB
    _Float16* h2f  = (_Float16*)alloc((size_t)kR * kE2 * 2);        //  0.5 MB
    float*    P    = (float*)alloc((size_t)8 * kR * kOUTC * 4);     // 33.6 MB

    // 0) front: gather + size-MLP 1+2 + weight converts in ONE launch
    hipLaunchKernelGGL(front_all, dim3(kFAll), dim3(256), 0, stream,
                       z, bb, W1, W2, O, S3, W1t, W2t, Ot, S3t,
                       S1, sb1, S2, sb2, h2f, x);

    // 1) dual fused GEMM: S3-embedding (64 blocks) + GEMM1 (320 blocks)
    hipLaunchKernelGGL(gemm_dual, dim3(64 + (kINNER / 128) * (kR / 128)), dim3(256), 0,
                       stream, h2f, S3t, sb3, xe + kOUTC, x, W1t, b1, h);

    // 2) xe[:, 0:1024] = h @ W2 + b2: split-K x8 (512 blocks = 2/CU, 20 k-steps)
    hipLaunchKernelGGL((gemm_f16_sk<8>), dim3(kOUTC / 128, kR / 128, 8), dim3(256), 0,
                       stream, h, W2t, P, kINNER);
    hipLaunchKernelGGL((reduce_splitk<false, true, 8>),
                       dim3((size_t)kR * kOUTC / 1024), dim3(256), 0, stream,
                       P, b2, xe, kOUTC, kXE);

    // 3) out = xe @ O + ob: split-K x8 (512 blocks = 2/CU, 8 k-steps)
    hipLaunchKernelGGL((gemm_f16_sk<8>), dim3(kOUTC / 128, kR / 128, 8), dim3(256), 0,
                       stream, xe, Ot, P, kXE);
    hipLaunchKernelGGL((reduce_splitk<false, false, 8>),
                       dim3((size_t)kR * kOUTC / 1024), dim3(256), 0, stream,
                       P, ob, out, kOUTC, kOUTC);
}

// Round 11
// 384.591 us; speedup vs baseline: 1.1364x; 1.0347x over previous
//
#include <hip/hip_runtime.h>

// Problem constants
static constexpr int kBS    = 8;
static constexpr int kNROI  = 128;
static constexpr int kR     = kBS * kNROI;   // 1024 rows
static constexpr int kCH    = 1280;
static constexpr int kH     = 64;
static constexpr int kW     = 64;
static constexpr int kPIX   = kH * kW;       // 4096
static constexpr int kINNER = 5120;
static constexpr int kOUTC  = 1024;
static constexpr int kXE    = 2 * kOUTC;     // 2048 concat width
static constexpr int kE2    = 256;           // size-MLP hidden 2

typedef _Float16 half8 __attribute__((ext_vector_type(8)));   // f16x8 MFMA A/B frag
typedef float floatx4 __attribute__((ext_vector_type(4)));    // MFMA C/D frag

// Async global->LDS 16B copy. LDS dest must be wave-uniform base + lane*16,
// which our chunk-index==threadIdx staging layout satisfies exactly.
__device__ __forceinline__ void gload_lds16(const _Float16* g, _Float16* l) {
    __builtin_amdgcn_global_load_lds(
        (const __attribute__((address_space(1))) void*)g,
        (__attribute__((address_space(3))) void*)l,
        16, 0, 0);
}

// ---------------------------------------------------------------------------
// FRONT mega-kernel: ROI gather (self-contained) + size-MLP 1+2 + weight
// converts in ONE launch.
// Round-11 changes vs round 10:
//  (a) z planes staged in LDS as F16 (numerics validated rounds 0-7):
//      LDS 47.6 -> 30.75 KB  => 5 blocks/CU (was 3) -- latency hiding.
//  (b) block roles INTERLEAVED (bid%3==0 -> gather among convs) so
//      latency-bound gather blocks and BW-bound conv blocks co-reside.
// Block counts: 5120 gather + 13824 conv + 256 mlp = 19200.
//   bid in [0,15360): bid%3==0 -> gather bid/3; else other (bid/3)*2+(bid%3)-1
//   bid in [15360,19200): other 10240 + (bid-15360)
//   other id < 13824 -> conv tile; else -> mlp block (id-13824)
// ---------------------------------------------------------------------------
static constexpr int kPC  = 2;      // planes per gather block
static constexpr int kPSh = 4104;   // padded plane stride in halfs
                                    // (8208B; word stride 2052 -> ch pair 4 banks apart)
static constexpr int kFAll = 19200;

__global__ __launch_bounds__(256) void front_all(const float* __restrict__ z,
                                                 const float* __restrict__ bboxes,
                                                 const float* __restrict__ W1,
                                                 const float* __restrict__ W2,
                                                 const float* __restrict__ O,
                                                 const float* __restrict__ S3,
                                                 _Float16* __restrict__ W1t,
                                                 _Float16* __restrict__ W2t,
                                                 _Float16* __restrict__ Ot,
                                                 _Float16* __restrict__ S3t,
                                                 const float* __restrict__ S1,
                                                 const float* __restrict__ sb1,
                                                 const float* __restrict__ S2,
                                                 const float* __restrict__ sb2,
                                                 _Float16* __restrict__ h2f,
                                                 _Float16* __restrict__ x) {
    // Gather layout (bytes): planes f16 [2][4104] = 16416 | ywL f32 [12][128] = 6144
    //                        | xwL f32 [12][128] = 6144 | meta int [4][128] = 2048
    __shared__ __align__(16) char smemRaw[30752];
    const int bid = blockIdx.x;
    const int t   = threadIdx.x;      // 0..255

    int gid = -1, oid = -1;
    if (bid < 15360) {
        if (bid % 3 == 0) gid = bid / 3;
        else              oid = (bid / 3) * 2 + (bid % 3) - 1;
    } else {
        oid = 10240 + (bid - 15360);
    }

    if (gid >= 0) {
        // ---- ROI gather from z planes, staged f16 in LDS ----
        _Float16* pl = (_Float16*)smemRaw;                 // [2][kPSh]
        float* ywL = (float*)(smemRaw + 16416);            // [12][128] (ic folded)
        float* xwL = ywL + 12 * 128;                       // [12][128]
        int*   im  = (int*)(xwL + 12 * 128);               // ymin|xmin|nyd|nxd x128
        const int b   = gid & 7;
        const int chg = gid >> 3;                // 0..639
        const int c0  = chg * kPC;
        const float* zb = z + ((size_t)b * kCH + c0) * kPIX;
        // stage 2 planes: 2048 float4 -> f16x4 (8B) stores, fully coalesced loads
#pragma unroll
        for (int i = 0; i < 8; ++i) {
            const int idx = t + i * 256;        // float4 index 0..2047
            const int ch  = idx >> 10;          // 0..1
            const int w4  = (idx & 1023) * 4;   // half offset in plane
            const float4 v = *(const float4*)&zb[(size_t)ch * kPIX + w4];
            union { _Float16 h[4]; uint2 u; } pk;
            pk.h[0] = (_Float16)v.x; pk.h[1] = (_Float16)v.y;
            pk.h[2] = (_Float16)v.z; pk.h[3] = (_Float16)v.w;
            *(uint2*)&pl[ch * kPSh + w4] = pk.u;
        }
        // build consolidated weight lists for all 128 ROIs of image b
        if (t < 128) {
            const int r = b * kNROI + t;
#pragma unroll
            for (int i = 0; i < 12; ++i) { ywL[i * 128 + t] = 0.0f; xwL[i * 128 + t] = 0.0f; }
            const float x1 = bboxes[r * 4 + 0] * 0.125f - 0.5f;
            const float y1 = bboxes[r * 4 + 1] * 0.125f - 0.5f;
            const float x2 = bboxes[r * 4 + 2] * 0.125f - 0.5f;
            const float y2 = bboxes[r * 4 + 3] * 0.125f - 0.5f;
            const float rw = x2 - x1, rh = y2 - y1;
            const float gwf = fminf(fmaxf(ceilf(rw), 1.0f), 8.0f);
            const float ghf = fminf(fmaxf(ceilf(rh), 1.0f), 8.0f);
            const int gw = (int)gwf, gh = (int)ghf;
            const float ic = 1.0f / (gwf * ghf);

            int ymin = 0, last = 0;
            for (int g = 0; g < gh; ++g) {
                const float c   = y1 + ((float)g + 0.5f) * rh / ghf;
                const bool oob  = (c < -1.0f) || (c > 64.0f);
                const float cc  = fmaxf(c, 0.0f);
                const float lo0 = floorf(cc);
                const bool hic  = (lo0 >= 63.0f);
                const int lo    = (int)fminf(lo0, 63.0f);
                const int hi    = (int)fminf(lo0 + 1.0f, 63.0f);
                const float fr  = hic ? 0.0f : (cc - lo0);
                const float m   = oob ? 0.0f : 1.0f;
                if (g == 0) ymin = lo;
                const int il = min(lo - ymin, 11);
                const int ih = min(hi - ymin, 11);
                ywL[il * 128 + t] += m * (1.0f - fr);
                ywL[ih * 128 + t] += m * fr;
                last = hi;
            }
            const int nyd = min(last - ymin + 1, 12);

            int xmin = 0; last = 0;
            for (int g = 0; g < gw; ++g) {
                const float c   = x1 + ((float)g + 0.5f) * rw / gwf;
                const bool oob  = (c < -1.0f) || (c > 64.0f);
                const float cc  = fmaxf(c, 0.0f);
                const float lo0 = floorf(cc);
                const bool hic  = (lo0 >= 63.0f);
                const int lo    = (int)fminf(lo0, 63.0f);
                const int hi    = (int)fminf(lo0 + 1.0f, 63.0f);
                const float fr  = hic ? 0.0f : (cc - lo0);
                const float m   = oob ? 0.0f : 1.0f;
                if (g == 0) xmin = lo;
                const int il = min(lo - xmin, 11);
                const int ih = min(hi - xmin, 11);
                xwL[il * 128 + t] += m * (1.0f - fr);
                xwL[ih * 128 + t] += m * fr;
                last = hi;
            }
            const int nxd = min(last - xmin + 1, 12);
#pragma unroll
            for (int i = 0; i < 12; ++i) ywL[i * 128 + t] *= ic;   // fold invCount
            im[t] = ymin; im[128 + t] = xmin; im[256 + t] = nyd; im[384 + t] = nxd;
        }
        __syncthreads();
        // gather: thread = (ch = t&1, ROI = t>>1); weights from LDS
        const int ch = t & 1;
        const int ri = t >> 1;                 // 0..127
        const int r  = b * kNROI + ri;
        const _Float16* plc = pl + ch * kPSh;
        const int ym = im[ri], xm = im[128 + ri];
        const int ny = im[256 + ri], nx = im[384 + ri];
        float acc = 0.0f;
        for (int iy = 0; iy < ny; ++iy) {
            const float wy = ywL[iy * 128 + ri];
            const int ro   = (ym + iy) * kW + xm;
            for (int ix = 0; ix < nx; ++ix)
                acc += wy * xwL[ix * 128 + ri] * (float)plc[ro + ix];
        }
        x[(size_t)r * kCH + c0 + ch] = (_Float16)acc;
    } else if (oid < 13824) {
        // ---- weight convert+transpose: W (K x N) fp32 -> Wt (N x K) f16 ----
        float* tileb = (float*)smemRaw;   // [32][33]
        const float* W; _Float16* Wt; int K, N, tile;
        if (oid < 6400)        { W = W1; Wt = W1t; K = kCH;    N = kINNER; tile = oid; }
        else if (oid < 11520)  { W = W2; Wt = W2t; K = kINNER; N = kOUTC;  tile = oid - 6400; }
        else if (oid < 13568)  { W = O;  Wt = Ot;  K = kXE;    N = kOUTC;  tile = oid - 11520; }
        else                   { W = S3; Wt = S3t; K = kE2;    N = kOUTC;  tile = oid - 13568; }
        const int nt = N / 32;
        const int n0 = (tile % nt) * 32;
        const int k0 = (tile / nt) * 32;
        {   // load 32x32 floats as 256 float4 (row = k-local, col = n-local)
            const int row = t >> 3;          // 0..31
            const int c4  = (t & 7) * 4;     // 0..28
            const float4 v = *(const float4*)&W[(size_t)(k0 + row) * N + n0 + c4];
            float* tl = tileb + row * 33 + c4;
            tl[0] = v.x; tl[1] = v.y; tl[2] = v.z; tl[3] = v.w;
        }
        __syncthreads();
        {   // transposed store: 4 k packed per thread -> uint2 (8B)
            const int n  = t >> 3;           // 0..31
            const int k4 = (t & 7) * 4;      // 0..28
            union { _Float16 h[4]; uint2 u; } pk;
#pragma unroll
            for (int j = 0; j < 4; ++j) pk.h[j] = (_Float16)tileb[(k4 + j) * 33 + n];
            *(uint2*)&Wt[(size_t)(n0 + n) * K + k0 + k4] = pk.u;
        }
    } else {
        // ---- size-MLP layers 1+2: 2 -> 64 -> 256, 4 rows/block ----
        const int r0 = (oid - 13824) * 4;
        float* sz = (float*)smemRaw;            // [4][2]
        float* h1 = (float*)smemRaw + 8;        // [4][64]
        if (t < 8) {
            const int row = t >> 1;
            const int c   = t & 1;
            const float* bb = bboxes + (size_t)(r0 + row) * 4;
            sz[row * 2 + c] = (c == 0) ? (bb[3] - bb[1]) : (bb[2] - bb[0]);
        }
        __syncthreads();
        {   // layer 1: 4 rows x 64 = 256 items, one per thread
            const int row = t >> 6;
            const int j   = t & 63;
            const float v = sz[row * 2] * S1[j] + sz[row * 2 + 1] * S1[64 + j] + sb1[j];
            h1[row * 64 + j] = fmaxf(v, 0.0f);
        }
        __syncthreads();
        {   // layer 2: j = t, 4 rows register-blocked
            float acc[4];
            const float b = sb2[t];
#pragma unroll
            for (int row = 0; row < 4; ++row) acc[row] = b;
#pragma unroll 16
            for (int k = 0; k < 64; ++k) {
                const float w = S2[k * 256 + t];
#pragma unroll
                for (int row = 0; row < 4; ++row) acc[row] += h1[row * 64 + k] * w;
            }
#pragma unroll
            for (int row = 0; row < 4; ++row)
                h2f[(size_t)(r0 + row) * kE2 + t] = (_Float16)fmaxf(acc[row], 0.0f);
        }
    }
}

// ---------------------------------------------------------------------------
// f16 MFMA GEMM (NT), 128x128 tile, BK=32, 256 threads = 4 waves.
// Double-buffered global_load_lds staging (verified rounds 3/5/6/7/9/10).
// Split-K partial (blockIdx.z), raw fp32 plane store -> P.
// ---------------------------------------------------------------------------
template <int NSPLIT>
__global__ __launch_bounds__(256) void gemm_f16_sk(const _Float16* __restrict__ A,
                                                   const _Float16* __restrict__ Bt,
                                                   float* __restrict__ P,
                                                   int Kfull) {
    __shared__ _Float16 As[2][128 * 32];
    __shared__ _Float16 Bs[2][128 * 32];
    const int t    = threadIdx.x;
    const int lane = t & 63;
    const int wave = t >> 6;
    const int m0 = blockIdx.y * 128, n0 = blockIdx.x * 128;
    const int Ksplit = Kfull / NSPLIT;
    const int s  = blockIdx.z;
    const int Nn = gridDim.x * 128;
    const int Mm = gridDim.y * 128;

    const int c0 = t, c1 = t + 256;
    const _Float16* Ag0 = A + (size_t)(m0 + (c0 >> 2)) * Kfull + (c0 & 3) * 8 + s * Ksplit;
    const _Float16* Ag1 = A + (size_t)(m0 + (c1 >> 2)) * Kfull + (c1 & 3) * 8 + s * Ksplit;
    const _Float16* Bg0 = Bt + (size_t)(n0 + (c0 >> 2)) * Kfull + (c0 & 3) * 8 + s * Ksplit;
    const _Float16* Bg1 = Bt + (size_t)(n0 + (c1 >> 2)) * Kfull + (c1 & 3) * 8 + s * Ksplit;

    const int wm = (wave >> 1) * 64;
    const int wn = (wave & 1) * 64;
    const int fm = lane & 15;
    const int kq = (lane >> 4) * 8;

    floatx4 acc[4][4];
#pragma unroll
    for (int i = 0; i < 4; ++i)
#pragma unroll
        for (int j = 0; j < 4; ++j) acc[i][j] = (floatx4){0.f, 0.f, 0.f, 0.f};

    const int nsteps = Ksplit / 32;
    gload_lds16(Ag0, &As[0][c0 * 8]);
    gload_lds16(Ag1, &As[0][c1 * 8]);
    gload_lds16(Bg0, &Bs[0][c0 * 8]);
    gload_lds16(Bg1, &Bs[0][c1 * 8]);
    __syncthreads();

    for (int ks = 0; ks < nsteps; ++ks) {
        const int cur = ks & 1;
        if (ks + 1 < nsteps) {
            const int kn = (ks + 1) * 32;
            gload_lds16(Ag0 + kn, &As[cur ^ 1][c0 * 8]);
            gload_lds16(Ag1 + kn, &As[cur ^ 1][c1 * 8]);
            gload_lds16(Bg0 + kn, &Bs[cur ^ 1][c0 * 8]);
            gload_lds16(Bg1 + kn, &Bs[cur ^ 1][c1 * 8]);
        }
        half8 af[4], bfv[4];
#pragma unroll
        for (int i = 0; i < 4; ++i)
            af[i] = *(const half8*)&As[cur][(wm + i * 16 + fm) * 32 + kq];
#pragma unroll
        for (int j = 0; j < 4; ++j)
            bfv[j] = *(const half8*)&Bs[cur][(wn + j * 16 + fm) * 32 + kq];
#pragma unroll
        for (int i = 0; i < 4; ++i)
#pragma unroll
            for (int j = 0; j < 4; ++j)
                acc[i][j] = __builtin_amdgcn_mfma_f32_16x16x32_f16(af[i], bfv[j], acc[i][j], 0, 0, 0);
        __syncthreads();
    }

    float* Pp = P + (size_t)s * Mm * Nn;
    const int qr = (lane >> 4) * 4;
#pragma unroll
    for (int j = 0; j < 4; ++j) {
        const int col = n0 + wn + j * 16 + fm;
#pragma unroll
        for (int i = 0; i < 4; ++i) {
            const int row = m0 + wm + i * 16 + qr;
#pragma unroll
            for (int rr = 0; rr < 4; ++rr)
                Pp[(size_t)(row + rr) * Nn + col] = acc[i][j][rr];
        }
    }
}

// ---------------------------------------------------------------------------
// DUAL fused GEMM: S3-embedding GEMM (64 blocks) + GEMM1 (320 blocks) in one
// launch (verified rounds 6/7/8/9/10).
// ---------------------------------------------------------------------------
__global__ __launch_bounds__(256) void gemm_dual(const _Float16* __restrict__ h2f,
                                                 const _Float16* __restrict__ S3t,
                                                 const float* __restrict__ sb3,
                                                 _Float16* __restrict__ xeR,
                                                 const _Float16* __restrict__ x,
                                                 const _Float16* __restrict__ W1t,
                                                 const float* __restrict__ b1,
                                                 _Float16* __restrict__ h) {
    __shared__ _Float16 As[2][128 * 32];
    __shared__ _Float16 Bs[2][128 * 32];
    const int bid = blockIdx.x;
    const _Float16* A; const _Float16* Bt; const float* bias; _Float16* Out;
    int Kfull, ldc, nbn, tile; bool relu;
    if (bid < 64) {
        A = h2f; Bt = S3t; bias = sb3; Out = xeR;
        Kfull = kE2; ldc = kXE; relu = false; nbn = kOUTC / 128; tile = bid;
    } else {
        A = x; Bt = W1t; bias = b1; Out = h;
        Kfull = kCH; ldc = kINNER; relu = true; nbn = kINNER / 128; tile = bid - 64;
    }
    const int n0 = (tile % nbn) * 128;
    const int m0 = (tile / nbn) * 128;

    const int t    = threadIdx.x;
    const int lane = t & 63;
    const int wave = t >> 6;

    const int c0 = t, c1 = t + 256;
    const _Float16* Ag0 = A + (size_t)(m0 + (c0 >> 2)) * Kfull + (c0 & 3) * 8;
    const _Float16* Ag1 = A + (size_t)(m0 + (c1 >> 2)) * Kfull + (c1 & 3) * 8;
    const _Float16* Bg0 = Bt + (size_t)(n0 + (c0 >> 2)) * Kfull + (c0 & 3) * 8;
    const _Float16* Bg1 = Bt + (size_t)(n0 + (c1 >> 2)) * Kfull + (c1 & 3) * 8;

    const int wm = (wave >> 1) * 64;
    const int wn = (wave & 1) * 64;
    const int fm = lane & 15;
    const int kq = (lane >> 4) * 8;

    floatx4 acc[4][4];
#pragma unroll
    for (int i = 0; i < 4; ++i)
#pragma unroll
        for (int j = 0; j < 4; ++j) acc[i][j] = (floatx4){0.f, 0.f, 0.f, 0.f};

    const int nsteps = Kfull / 32;
    gload_lds16(Ag0, &As[0][c0 * 8]);
    gload_lds16(Ag1, &As[0][c1 * 8]);
    gload_lds16(Bg0, &Bs[0][c0 * 8]);
    gload_lds16(Bg1, &Bs[0][c1 * 8]);
    __syncthreads();

    for (int ks = 0; ks < nsteps; ++ks) {
        const int cur = ks & 1;
        if (ks + 1 < nsteps) {
            const int kn = (ks + 1) * 32;
            gload_lds16(Ag0 + kn, &As[cur ^ 1][c0 * 8]);
            gload_lds16(Ag1 + kn, &As[cur ^ 1][c1 * 8]);
            gload_lds16(Bg0 + kn, &Bs[cur ^ 1][c0 * 8]);
            gload_lds16(Bg1 + kn, &Bs[cur ^ 1][c1 * 8]);
        }
        half8 af[4], bfv[4];
#pragma unroll
        for (int i = 0; i < 4; ++i)
            af[i] = *(const half8*)&As[cur][(wm + i * 16 + fm) * 32 + kq];
#pragma unroll
        for (int j = 0; j < 4; ++j)
            bfv[j] = *(const half8*)&Bs[cur][(wn + j * 16 + fm) * 32 + kq];
#pragma unroll
        for (int i = 0; i < 4; ++i)
#pragma unroll
            for (int j = 0; j < 4; ++j)
                acc[i][j] = __builtin_amdgcn_mfma_f32_16x16x32_f16(af[i], bfv[j], acc[i][j], 0, 0, 0);
        __syncthreads();
    }

    // Epilogue: bias (+relu) -> f16 at ldc. C/D: col = lane&15, row = (lane>>4)*4+rr
    const int qr = (lane >> 4) * 4;
#pragma unroll
    for (int j = 0; j < 4; ++j) {
        const int col = n0 + wn + j * 16 + fm;
        const float bv = bias[col];
#pragma unroll
        for (int i = 0; i < 4; ++i) {
            const int row = m0 + wm + i * 16 + qr;
#pragma unroll
            for (int rr = 0; rr < 4; ++rr) {
                float v = acc[i][j][rr] + bv;
                if (relu) v = fmaxf(v, 0.f);
                Out[(size_t)(row + rr) * ldc + col] = (_Float16)v;
            }
        }
    }
}

// ---------------------------------------------------------------------------
// Split-K reduce + bias + (relu) + convert.
// ---------------------------------------------------------------------------
template <bool RELU, bool F16OUT, int NSPLIT>
__global__ __launch_bounds__(256) void reduce_splitk(const float* __restrict__ P,
                                                     const float* __restrict__ bias,
                                                     void* __restrict__ Cout,
                                                     int Nn, int ldc) {
    const size_t idx = ((size_t)blockIdx.x * 256 + threadIdx.x) * 4;
    const size_t MN  = (size_t)gridDim.x * 1024;
    const int m = (int)(idx / (size_t)Nn);
    const int n = (int)(idx % (size_t)Nn);
    float4 acc = *(const float4*)(P + idx);
#pragma unroll
    for (int s = 1; s < NSPLIT; ++s) {
        const float4 v = *(const float4*)(P + (size_t)s * MN + idx);
        acc.x += v.x; acc.y += v.y; acc.z += v.z; acc.w += v.w;
    }
    const float4 b4 = *(const float4*)(bias + n);
    acc.x += b4.x; acc.y += b4.y; acc.z += b4.z; acc.w += b4.w;
    if (RELU) {
        acc.x = fmaxf(acc.x, 0.f); acc.y = fmaxf(acc.y, 0.f);
        acc.z = fmaxf(acc.z, 0.f); acc.w = fmaxf(acc.w, 0.f);
    }
    if (F16OUT) {
        union { _Float16 h[4]; uint2 u; } pk;
        pk.h[0] = (_Float16)acc.x; pk.h[1] = (_Float16)acc.y;
        pk.h[2] = (_Float16)acc.z; pk.h[3] = (_Float16)acc.w;
        *(uint2*)((_Float16*)Cout + (size_t)m * ldc + n) = pk.u;
    } else {
        *(float4*)((float*)Cout + (size_t)m * ldc + n) = acc;
    }
}

// ---------------------------------------------------------------------------
extern "C" void kernel_launch(void* const* d_in, const int* in_sizes, int n_in,
                              void* d_out, int out_size, void* d_ws, size_t ws_size,
                              hipStream_t stream) {
    (void)in_sizes; (void)n_in; (void)out_size; (void)ws_size;
    const float* z   = (const float*)d_in[0];
    const float* bb  = (const float*)d_in[1];
    const float* W1  = (const float*)d_in[2];
    const float* b1  = (const float*)d_in[3];
    const float* W2  = (const float*)d_in[4];
    const float* b2  = (const float*)d_in[5];
    const float* S1  = (const float*)d_in[6];
    const float* sb1 = (const float*)d_in[7];
    const float* S2  = (const float*)d_in[8];
    const float* sb2 = (const float*)d_in[9];
    const float* S3  = (const float*)d_in[10];
    const float* sb3 = (const float*)d_in[11];
    const float* O   = (const float*)d_in[12];
    const float* ob  = (const float*)d_in[13];
    float* out = (float*)d_out;

    char* ws = (char*)d_ws;
    size_t off = 0;
    auto alloc = [&](size_t bytes) {
        void* p = ws + off;
        off += (bytes + 255) & ~(size_t)255;
        return p;
    };
    _Float16* x    = (_Float16*)alloc((size_t)kR * kCH * 2);        //  2.6 MB
    _Float16* h    = (_Float16*)alloc((size_t)kR * kINNER * 2);     // 10.5 MB
    _Float16* xe   = (_Float16*)alloc((size_t)kR * kXE * 2);        //  4.2 MB
    _Float16* W1t  = (_Float16*)alloc((size_t)kINNER * kCH * 2);    // 13.1 MB
    _Float16* W2t  = (_Float16*)alloc((size_t)kOUTC * kINNER * 2);  // 10.5 MB
    _Float16* Ot   = (_Float16*)alloc((size_t)kOUTC * kXE * 2);     //  4.2 MB
    _Float16* S3t  = (_Float16*)alloc((size_t)kOUTC * kE2 * 2);     //  0.5 MB
    _Float16* h2f  = (_Float16*)alloc((size_t)kR * kE2 * 2);        //  0.5 MB
    float*    P    = (float*)alloc((size_t)8 * kR * kOUTC * 4);     // 33.6 MB

    // 0) front: gather + size-MLP 1+2 + weight converts in ONE launch
    hipLaunchKernelGGL(front_all, dim3(kFAll), dim3(256), 0, stream,
                       z, bb, W1, W2, O, S3, W1t, W2t, Ot, S3t,
                       S1, sb1, S2, sb2, h2f, x);

    // 1) dual fused GEMM: S3-embedding (64 blocks) + GEMM1 (320 blocks)
    hipLaunchKernelGGL(gemm_dual, dim3(64 + (kINNER / 128) * (kR / 128)), dim3(256), 0,
                       stream, h2f, S3t, sb3, xe + kOUTC, x, W1t, b1, h);

    // 2) xe[:, 0:1024] = h @ W2 + b2: split-K x8 (512 blocks = 2/CU, 20 k-steps)
    hipLaunchKernelGGL((gemm_f16_sk<8>), dim3(kOUTC / 128, kR / 128, 8), dim3(256), 0,
                       stream, h, W2t, P, kINNER);
    hipLaunchKernelGGL((reduce_splitk<false, true, 8>),
                       dim3((size_t)kR * kOUTC / 1024), dim3(256), 0, stream,
                       P, b2, xe, kOUTC, kXE);

    // 3) out = xe @ O + ob: split-K x8 (512 blocks = 2/CU, 8 k-steps)
    hipLaunchKernelGGL((gemm_f16_sk<8>), dim3(kOUTC / 128, kR / 128, 8), dim3(256), 0,
                       stream, xe, Ot, P, kXE);
    hipLaunchKernelGGL((reduce_splitk<false, false, 8>),
                       dim3((size_t)kR * kOUTC / 1024), dim3(256), 0, stream,
                       P, ob, out, kOUTC, kOUTC);
}